// Round 2
// baseline (735.363 us; speedup 1.0000x reference)
//
#include <hip/hip_runtime.h>
#include <stdint.h>

#define BB 32
#define DD 256
#define TT 1024
#define KK 8192

typedef __attribute__((ext_vector_type(2))) float f2;
typedef __attribute__((ext_vector_type(4))) float f4;
typedef __attribute__((ext_vector_type(8))) _Float16 hfrag;  // 8 f16 = 4 VGPR
typedef __attribute__((ext_vector_type(4))) float f4acc;     // MFMA acc

#if __has_builtin(__builtin_elementwise_fma)
#define PKFMA(a, b, c) __builtin_elementwise_fma(a, b, c)
#else
static __device__ __forceinline__ f2 pkfma_(f2 a, f2 b, f2 c) {
    f2 r; r.x = __fmaf_rn(a.x, b.x, c.x); r.y = __fmaf_rn(a.y, b.y, c.y); return r;
}
#define PKFMA(a, b, c) pkfma_(a, b, c)
#endif

#define GLD16(gp, lp)                                                          \
    __builtin_amdgcn_global_load_lds(                                          \
        (const __attribute__((address_space(1))) uint32_t*)(gp),               \
        (__attribute__((address_space(3))) uint32_t*)(lp), 16, 0, 0)

#define MU 3.0e-4f
#define BCAP 4096
#define LIST_CAP 1048576
// e is pre-scaled by 1024 before fp16 cast; dist = Af+Bf - 2*dot/1024
#define INV512 0.001953125f

// ---------------- fast-path ws layout (bytes) ----------------
#define WS_LOSS   0            // double
#define WS_CNT    8            // int (overflow count)
#define WS_BCNT   16           // int[256]
#define WS_BF     1088
#define WS_AF     33856
#define WS_IDX    164928
#define WS_WIN    296000
#define WS_ZT     558144
#define WS_TMIN   34112576
#define WS_BKT    67667008
#define WS_LIST   71861312
#define WS_ZF     76055616     // fp16 z   [32768][256] = 16.8 MB
#define WS_EF     92832832     // fp16 e*1024 [8192][256] = 4.2 MB
#define WS_NEED   97027136

__device__ __forceinline__ unsigned short h16(float x) {
    _Float16 t = (_Float16)x;                    // RNE
    return __builtin_bit_cast(unsigned short, t);
}

// Bit-exact numpy pairwise_sum of x[i]^2, n=256.
__device__ __forceinline__ float np_sq_sum256(const float* __restrict__ base, int stride) {
    float res[2];
    #pragma unroll
    for (int blk = 0; blk < 2; ++blk) {
        const int o = blk * 128;
        float r[8];
        #pragma unroll
        for (int j = 0; j < 8; ++j) {
            const float x = base[(o + j) * stride];
            r[j] = __fmul_rn(x, x);
        }
        for (int i = 8; i < 128; i += 8) {
            #pragma unroll
            for (int j = 0; j < 8; ++j) {
                const float x = base[(o + i + j) * stride];
                r[j] = __fadd_rn(r[j], __fmul_rn(x, x));
            }
        }
        res[blk] = __fadd_rn(__fadd_rn(__fadd_rn(r[0], r[1]), __fadd_rn(r[2], r[3])),
                             __fadd_rn(__fadd_rn(r[4], r[5]), __fadd_rn(r[6], r[7])));
    }
    return __fadd_rn(res[0], res[1]);
}

__global__ __launch_bounds__(256) void bsum_kernel(const float* __restrict__ emb,
                                                   float* __restrict__ Bf) {
    const int k = blockIdx.x * 256 + threadIdx.x;
    Bf[k] = np_sq_sum256(emb + (size_t)k * DD, 1);
}

__global__ __launch_bounds__(256) void asum_kernel(const float* __restrict__ z_e,
                                                   float* __restrict__ Af) {
    const int n = blockIdx.x * 256 + threadIdx.x;
    const int b = n >> 10, t = n & 1023;
    Af[n] = np_sq_sum256(z_e + ((size_t)b << 18) + t, TT);
}

// ---- fused z prep: zt (fp32 [q][d]) + zf (fp16) + Af, one pass ----
__global__ __launch_bounds__(256) void fusedz_kernel(const float* __restrict__ z_e,
                                                     float* __restrict__ zt,
                                                     unsigned short* __restrict__ zf,
                                                     float* __restrict__ Af) {
    __shared__ float tile[64 * 261];
    const int tid = threadIdx.x, l = tid & 63, r = tid >> 6;
    const int n0 = blockIdx.x * 64;           // 512 blocks
    const int b = n0 >> 10, t0 = n0 & 1023;
    for (int d = r; d < DD; d += 4)
        tile[l * 261 + d] = z_e[(size_t)(b * DD + d) * TT + t0 + l];
    __syncthreads();
    const int q = tid >> 2, c0 = (tid & 3) * 64;
    const float* src = &tile[q * 261 + c0];
    float* dzt = zt + (size_t)(n0 + q) * DD + c0;
    unsigned short* dzf = zf + (size_t)(n0 + q) * DD + c0;
    #pragma unroll
    for (int i = 0; i < 16; ++i) {
        f4 v;
        v.x = src[4 * i + 0]; v.y = src[4 * i + 1];
        v.z = src[4 * i + 2]; v.w = src[4 * i + 3];
        *(f4*)(dzt + 4 * i) = v;
        ushort4 h;
        h.x = h16(v.x); h.y = h16(v.y); h.z = h16(v.z); h.w = h16(v.w);
        *(ushort4*)(dzf + 4 * i) = h;
    }
    if (tid < 64) Af[n0 + tid] = np_sq_sum256(&tile[tid * 261], 1);
}

// ---- e -> fp16, scaled by 1024 (exact pow2) to stay in fp16 normal range ----
__global__ __launch_bounds__(256) void convef_kernel(const float* __restrict__ emb,
                                                     unsigned short* __restrict__ ef) {
    const int i0 = (blockIdx.x * 256 + threadIdx.x) * 4;
    const f4 v = *(const f4*)(emb + i0);
    ushort4 h;
    h.x = h16(v.x * 1024.0f); h.y = h16(v.y * 1024.0f);
    h.z = h16(v.z * 1024.0f); h.w = h16(v.w * 1024.0f);
    *(ushort4*)(ef + i0) = h;
}

// ---- K1: fp16 MFMA scorer, pipelined ----
// 2048 blocks (256 qt x 8 kslab), 512 threads = 8 waves (wq = w&3: 32 q-rows,
// wk = w>>2: 64-code half of each 128-code k-tile). A (z) entirely in registers
// (fragment layout identical to the verified LDS path). B (e) streams through
// 2x16KB double-buffered LDS chunks (128 codes x 64 dims) with counted
// s_waitcnt vmcnt(2) + raw s_barrier -- loads stay in flight across barriers.
// Per-ktile min epilogue runs in the load shadow; Bf comes from LDS so its
// reads don't pollute vmcnt. tmp_min accumulated in LDS, written coalesced.
__global__ __launch_bounds__(512) void mfma1_kernel(
    const unsigned short* __restrict__ zf, const unsigned short* __restrict__ ef,
    const float* __restrict__ Af, const float* __restrict__ Bf,
    float* __restrict__ tmp_min) {
    __shared__ unsigned short Bb[2][8192];   // 2 x 16 KiB B chunks
    __shared__ float minbuf[128][32];        // 16 KiB per-block tmp_min
    __shared__ float BfL[1024];              // 4 KiB Bf slice

    const int tid  = threadIdx.x;
    const int lane = tid & 63;
    const int w    = tid >> 6;          // 0..7
    const int quad = lane >> 4;
    const int l15  = lane & 15;
    const int wq   = w & 3;             // q-group of 32 rows
    const int wk   = w >> 2;            // 64-code half within a 128-code ktile
    const int qt   = blockIdx.x >> 3;   // 256 q-tiles of 128
    const int kb   = blockIdx.x & 7;    // 8 k-slabs of 1024 codes

    // ---- Bf slice -> LDS ----
    BfL[tid]       = Bf[kb * 1024 + tid];
    BfL[tid + 512] = Bf[kb * 1024 + tid + 512];

    // ---- A into registers: 32 q-rows x 256 dims, fragment layout ----
    hfrag a_reg[2][8];
    {
        const unsigned short* abase =
            zf + (size_t)(qt * 128 + wq * 32 + l15) * DD + quad * 8;
        #pragma unroll
        for (int a = 0; a < 2; ++a)
            #pragma unroll
            for (int kc = 0; kc < 8; ++kc)
                a_reg[a][kc] = *(const hfrag*)(abase + (size_t)a * 16 * DD + kc * 32);
    }
    float af[2][4];
    #pragma unroll
    for (int a = 0; a < 2; ++a)
        #pragma unroll
        for (int r = 0; r < 4; ++r)
            af[a][r] = Af[qt * 128 + wq * 32 + a * 16 + quad * 4 + r];

    // staging source: wave w stages rowgroup w (codes 16w..16w+16) of each ktile
    const unsigned short* bsrc =
        ef + (size_t)(kb * 1024 + 16 * w + l15) * DD + quad * 8;

    __syncthreads();   // BfL visible before first epilogue

    f4acc acc[2][4];
    #pragma unroll
    for (int a = 0; a < 2; ++a)
        #pragma unroll
        for (int j = 0; j < 4; ++j) acc[a][j] = (f4acc){0.f, 0.f, 0.f, 0.f};

    // stage chunk (ktarg, sarg) into dp (wave's rowgroup slot of a buffer)
    #define STAGE_CHUNK(ktarg, sarg, dp) do {                                  \
        const unsigned short* sp_ = bsrc + (size_t)(ktarg) * 128 * DD + (sarg) * 64; \
        GLD16(sp_,      (dp));                                                 \
        GLD16(sp_ + 32, (dp) + 512);                                           \
    } while (0)

    // per-ktile min epilogue (reads acc, writes minbuf, resets acc)
    #define EPILOGUE(ktv) do {                                                 \
        float bfv_[4];                                                         \
        _Pragma("unroll")                                                      \
        for (int j = 0; j < 4; ++j)                                            \
            bfv_[j] = BfL[(ktv) * 128 + wk * 64 + j * 16 + l15];               \
        _Pragma("unroll")                                                      \
        for (int a = 0; a < 2; ++a) {                                          \
            _Pragma("unroll")                                                  \
            for (int r = 0; r < 4; ++r) {                                      \
                const float base_ = af[a][r];                                  \
                _Pragma("unroll")                                              \
                for (int jp = 0; jp < 2; ++jp) {                               \
                    const float c0_ = acc[a][2 * jp][r];                       \
                    const float c1_ = acc[a][2 * jp + 1][r];                   \
                    const float d0_ = __fmaf_rn(c0_, -INV512, base_ + bfv_[2 * jp]); \
                    const float d1_ = __fmaf_rn(c1_, -INV512, base_ + bfv_[2 * jp + 1]); \
                    float v_ = fminf(d0_, d1_);                                \
                    _Pragma("unroll")                                          \
                    for (int off = 1; off < 16; off <<= 1)                     \
                        v_ = fminf(v_, __shfl_xor(v_, off));                   \
                    if (l15 == 0)                                              \
                        minbuf[wq * 32 + a * 16 + quad * 4 + r]                \
                              [(ktv) * 4 + wk * 2 + jp] = v_;                  \
                }                                                              \
            }                                                                  \
        }                                                                      \
        _Pragma("unroll")                                                      \
        for (int a = 0; a < 2; ++a)                                            \
            _Pragma("unroll")                                                  \
            for (int j = 0; j < 4; ++j) acc[a][j] = (f4acc){0.f, 0.f, 0.f, 0.f}; \
    } while (0)

    STAGE_CHUNK(0, 0, &Bb[0][w * 1024]);

    for (int kt = 0; kt < 8; ++kt) {
        #pragma unroll
        for (int s = 0; s < 4; ++s) {
            const int last = (kt == 7) && (s == 3);
            if (!last) {
                const int kt_n = (s == 3) ? kt + 1 : kt;
                const int s_n  = (s + 1) & 3;
                STAGE_CHUNK(kt_n, s_n, &Bb[(s + 1) & 1][w * 1024]);
            }
            if (s == 0 && kt > 0) EPILOGUE(kt - 1);   // in the load shadow
            if (!last) asm volatile("s_waitcnt vmcnt(2)" ::: "memory");
            else       asm volatile("s_waitcnt vmcnt(0)" ::: "memory");
            __builtin_amdgcn_s_barrier();
            __builtin_amdgcn_sched_barrier(0);
            const unsigned short* bp = &Bb[s & 1][wk * 4096];
            #pragma unroll
            for (int h = 0; h < 2; ++h) {
                hfrag b[4];
                #pragma unroll
                for (int j = 0; j < 4; ++j)
                    b[j] = *(const hfrag*)(bp + j * 1024 + h * 512 + lane * 8);
                #pragma unroll
                for (int a = 0; a < 2; ++a)
                    #pragma unroll
                    for (int j = 0; j < 4; ++j)
                        acc[a][j] = __builtin_amdgcn_mfma_f32_16x16x32_f16(
                            a_reg[a][2 * s + h], b[j], acc[a][j], 0, 0, 0);
            }
            __builtin_amdgcn_sched_barrier(0);
            __builtin_amdgcn_s_barrier();
        }
    }
    EPILOGUE(7);

    __syncthreads();
    // coalesced tmp_min write: 128 rows x 32 groups = 16 KiB, full 64B lines
    {
        const int qloc = tid >> 2, c0 = (tid & 3) * 8;
        const f4 v0 = *(const f4*)&minbuf[qloc][c0];
        const f4 v1 = *(const f4*)&minbuf[qloc][c0 + 4];
        float* dst = tmp_min + (size_t)(qt * 128 + qloc) * 256 + kb * 32 + c0;
        *(f4*)dst       = v0;
        *(f4*)(dst + 4) = v1;
    }
    #undef STAGE_CHUNK
    #undef EPILOGUE
}

// ---- K2: fused select: per-q min+thr, winner init, bucket scatter ----
__global__ __launch_bounds__(256) void select_kernel(
    const float* __restrict__ tmp_min, int* __restrict__ bcnt,
    int* __restrict__ bucket, int* __restrict__ list, int* __restrict__ cnt,
    unsigned long long* __restrict__ winner) {
    const int tid = threadIdx.x, lane = tid & 63, w = tid >> 6;
    const int q = blockIdx.x * 4 + w;          // 8192 blocks
    const f4 v = *(const f4*)(tmp_min + (size_t)q * 256 + lane * 4);
    float m = fminf(fminf(v.x, v.y), fminf(v.z, v.w));
    #pragma unroll
    for (int off = 1; off < 64; off <<= 1) m = fminf(m, __shfl_xor(m, off));
    const float thr = m + MU;
    if (lane == 0) winner[q] = ~0ULL;
    float vv[4] = {v.x, v.y, v.z, v.w};
    #pragma unroll
    for (int j = 0; j < 4; ++j) {
        if (vv[j] <= thr) {
            const int g = lane * 4 + j;
            const int pos = atomicAdd(&bcnt[g], 1);
            if (pos < BCAP) bucket[g * BCAP + pos] = q;
            else {
                const int op = atomicAdd(cnt, 1);
                if (op < LIST_CAP) list[op] = (q << 8) | g;
            }
        }
    }
}

// ---- K3: bucketed exact re-rank: block per 32-code group, e staged once ----
__global__ __launch_bounds__(256) void rescan_bucket_kernel(
    const float* __restrict__ zt, const float* __restrict__ emb,
    const float* __restrict__ Af, const float* __restrict__ Bf,
    const int* __restrict__ bcnt, const int* __restrict__ bucket,
    unsigned long long* __restrict__ winner) {
    __shared__ float elds[256 * 33];   // [d][k], stride 33 -> conflict-free
    __shared__ float zbuf[8][256];
    __shared__ float bfs[32];
    const int g = blockIdx.x;          // 256 groups
    const int tid = threadIdx.x, lane = tid & 63, w = tid >> 6;
    const int half = lane >> 5, l32 = lane & 31, slot = w * 2 + half;
    {   // stage e rows (coalesced reads, transpose into [d][k])
        const int k = tid >> 3, s0 = (tid & 7) * 32;
        const float* src = emb + (size_t)(g * 32 + k) * DD + s0;
        #pragma unroll
        for (int i = 0; i < 8; ++i) {
            const f4 v = *(const f4*)(src + i * 4);
            elds[(s0 + 4 * i + 0) * 33 + k] = v.x;
            elds[(s0 + 4 * i + 1) * 33 + k] = v.y;
            elds[(s0 + 4 * i + 2) * 33 + k] = v.z;
            elds[(s0 + 4 * i + 3) * 33 + k] = v.w;
        }
        if (tid < 32) bfs[tid] = Bf[g * 32 + tid];
    }
    __syncthreads();
    const int nit = min(bcnt[g], BCAP);
    const int kme = g * 32 + l32;
    for (int base = 0; base < nit; base += 8) {
        const int it = base + slot;
        int q = -1;
        if (it < nit) {
            q = bucket[g * BCAP + it];
            f4* zb = (f4*)&zbuf[slot][0];
            const f4* zsrc = (const f4*)(zt + (size_t)q * DD);
            zb[l32]      = zsrc[l32];
            zb[l32 + 32] = zsrc[l32 + 32];
        }
        __syncthreads();
        if (it < nit) {
            const float* zp = &zbuf[slot][0];
            float c = 0.0f;
            #pragma unroll 8
            for (int d = 0; d < DD; ++d)
                c = __fmaf_rn(zp[d], elds[d * 33 + l32], c);
            float bv = __fsub_rn(__fadd_rn(Af[q], bfs[l32]), __fadd_rn(c, c));
            int bk = kme;
            #pragma unroll
            for (int off = 1; off < 32; off <<= 1) {
                const float ob = __shfl_xor(bv, off);
                const int   ok = __shfl_xor(bk, off);
                if (ob < bv || (ob == bv && ok < bk)) { bv = ob; bk = ok; }
            }
            if (l32 == 0)
                atomicMin(winner + q,
                          (((unsigned long long)__float_as_uint(bv)) << 32) | (unsigned)bk);
        }
        __syncthreads();
    }
}

// ---- K3x: overflow re-rank (per-item, rare) ----
__global__ __launch_bounds__(256) void rescan2_kernel(
    const float* __restrict__ zt, const float* __restrict__ emb,
    const float* __restrict__ Af, const float* __restrict__ Bf,
    const int* __restrict__ list, const int* __restrict__ cnt,
    unsigned long long* __restrict__ winner) {
    __shared__ float zbuf[8][256];
    const int tid = threadIdx.x, lane = tid & 63, w = tid >> 6;
    const int half = lane >> 5, l32 = lane & 31;
    const int slot = blockIdx.x * 8 + w * 2 + half;
    const int slots = gridDim.x * 8;
    const int n = min(*cnt, LIST_CAP);
    f4* zb = (f4*)&zbuf[w * 2 + half][0];
    for (int it = slot; it < n; it += slots) {
        const int id = list[it];
        const int q = id >> 8, g = id & 255;
        const f4* zsrc = (const f4*)(zt + (size_t)q * DD);
        zb[l32]      = zsrc[l32];
        zb[l32 + 32] = zsrc[l32 + 32];
        const int k = g * 32 + l32;
        const f4* e = (const f4*)(emb + (size_t)k * DD);
        float c = 0.0f;
        #pragma unroll 8
        for (int i = 0; i < 64; ++i) {
            const f4 ev = e[i];
            const f4 zv = zb[i];
            c = __fmaf_rn(zv.x, ev.x, c);
            c = __fmaf_rn(zv.y, ev.y, c);
            c = __fmaf_rn(zv.z, ev.z, c);
            c = __fmaf_rn(zv.w, ev.w, c);
        }
        float bv = __fsub_rn(__fadd_rn(Af[q], Bf[k]), __fadd_rn(c, c));
        int bk = k;
        #pragma unroll
        for (int off = 1; off < 32; off <<= 1) {
            const float ob = __shfl_xor(bv, off);
            const int   ok = __shfl_xor(bk, off);
            if (ob < bv || (ob == bv && ok < bk)) { bv = ob; bk = ok; }
        }
        if (l32 == 0)
            atomicMin(winner + q,
                      (((unsigned long long)__float_as_uint(bv)) << 32) | (unsigned)bk);
    }
}

// ---- K4: finalize idx + loss ----
__global__ __launch_bounds__(256) void final_kernel(
    const unsigned long long* __restrict__ winner, float* __restrict__ out_idx,
    int* __restrict__ idx_i, double* __restrict__ loss_acc) {
    __shared__ double ls[4];
    const int tid = threadIdx.x, lane = tid & 63, w = tid >> 6;
    const int q = blockIdx.x * 256 + tid;
    const unsigned long long wv = winner[q];
    const int k = (int)(wv & 0xFFFFFFFFu);
    idx_i[q] = k;
    out_idx[q] = (float)k;
    double s = (double)__uint_as_float((unsigned)(wv >> 32));
    #pragma unroll
    for (int off = 1; off < 64; off <<= 1) s += __shfl_xor(s, off);
    if (lane == 0) ls[w] = s;
    __syncthreads();
    if (tid == 0) atomicAdd(loss_acc, ls[0] + ls[1] + ls[2] + ls[3]);
}

// ================== r5 fallback scorer (ws too small) ==================
__device__ __forceinline__ void ldstage(const float* __restrict__ emb, int st,
                                        int c, int p, f4* g) {
    const int kt = st >> 4, dc = st & 15;
    const float* src = emb + (((size_t)(kt * 512 + p * 128 + c)) << 8) + dc * 16;
    #pragma unroll
    for (int m = 0; m < 4; ++m) g[m] = *(const f4*)(src + 4 * m);
    const float* src2 = src + (64 << 8);
    #pragma unroll
    for (int m = 0; m < 4; ++m) g[4 + m] = *(const f4*)(src2 + 4 * m);
}

__global__ __launch_bounds__(256, 2) void score5_kernel(
    const float* __restrict__ z_e, const float* __restrict__ emb,
    const float* __restrict__ Bf, const float* __restrict__ Af,
    float* __restrict__ out_idx, int* __restrict__ idx_i,
    double* __restrict__ loss_acc) {
    __shared__ float zl[32 * 260];
    __shared__ float etp[64 * 132];
    const int tid = threadIdx.x;
    const int lane = tid & 63;
    const int w = tid >> 6;
    const int n0 = blockIdx.x * 32;
    const int b = n0 >> 10, t0 = n0 & 1023;
    {
        const int q = tid & 31;
        for (int d = tid >> 5; d < DD; d += 8)
            zl[q * 260 + d] = z_e[((size_t)(b * DD + d) << 10) + t0 + q];
    }
    float Aq[8];
    #pragma unroll
    for (int j = 0; j < 8; ++j) Aq[j] = Af[n0 + w * 8 + j];
    float best[8];
    int bidx[8];
    #pragma unroll
    for (int j = 0; j < 8; ++j) { best[j] = 3.0e38f; bidx[j] = 0; }
    f4 g[8];
    ldstage(emb, 0, lane, w, g);
    for (int kt = 0; kt < 16; ++kt) {
        f2 acc[8][4];
        #pragma unroll
        for (int j = 0; j < 8; ++j)
            #pragma unroll
            for (int p2 = 0; p2 < 4; ++p2) acc[j][p2] = (f2){0.0f, 0.0f};
        for (int dc = 0; dc < 16; ++dc) {
            __syncthreads();
            {
                float* dst = etp + lane * 132 + w * 32;
                #pragma unroll
                for (int m = 0; m < 4; ++m) {
                    const f4 a = g[m], bv = g[4 + m];
                    *(f4*)(dst + 8 * m)     = __builtin_shufflevector(a, bv, 0, 4, 1, 5);
                    *(f4*)(dst + 8 * m + 4) = __builtin_shufflevector(a, bv, 2, 6, 3, 7);
                }
            }
            __syncthreads();
            const int st = kt * 16 + dc;
            ldstage(emb, st < 255 ? st + 1 : 255, lane, w, g);
            #pragma unroll
            for (int s4 = 0; s4 < 4; ++s4) {
                const int dd0 = s4 * 4;
                f4 zv[8];
                #pragma unroll
                for (int j = 0; j < 8; ++j)
                    zv[j] = *(const f4*)(zl + (w * 8 + j) * 260 + dc * 16 + dd0);
                f4 ev[4][2];
                #pragma unroll
                for (int p2 = 0; p2 < 4; ++p2) {
                    const float* eb = etp + lane * 132 + p2 * 32 + dd0 * 2;
                    ev[p2][0] = *(const f4*)(eb);
                    ev[p2][1] = *(const f4*)(eb + 4);
                }
                #pragma unroll
                for (int j = 0; j < 8; ++j) {
                    #pragma unroll
                    for (int dd = 0; dd < 4; ++dd) {
                        const float zs = zv[j][dd];
                        const f2 z2 = {zs, zs};
                        #pragma unroll
                        for (int p2 = 0; p2 < 4; ++p2) {
                            const f4 evv = ev[p2][dd >> 1];
                            const f2 e2 = (dd & 1)
                                ? __builtin_shufflevector(evv, evv, 2, 3)
                                : __builtin_shufflevector(evv, evv, 0, 1);
                            acc[j][p2] = PKFMA(z2, e2, acc[j][p2]);
                        }
                    }
                }
            }
        }
        const int kt0 = kt * 512;
        float Bk[8];
        #pragma unroll
        for (int i = 0; i < 8; ++i) Bk[i] = Bf[kt0 + 64 * i + lane];
        #pragma unroll
        for (int p2 = 0; p2 < 4; ++p2) {
            #pragma unroll
            for (int s = 0; s < 2; ++s) {
                const int i = 2 * p2 + s;
                #pragma unroll
                for (int j = 0; j < 8; ++j) {
                    const float C = s ? acc[j][p2].y : acc[j][p2].x;
                    const float dist = __fsub_rn(__fadd_rn(Aq[j], Bk[i]), __fadd_rn(C, C));
                    const int k = kt0 + 64 * i + lane;
                    if (dist < best[j]) { best[j] = dist; bidx[j] = k; }
                }
            }
        }
    }
    #pragma unroll
    for (int j = 0; j < 8; ++j) {
        float bb = best[j];
        int bi = bidx[j];
        #pragma unroll
        for (int off = 1; off < 64; off <<= 1) {
            const float ob = __shfl_xor(bb, off);
            const int oi = __shfl_xor(bi, off);
            if (ob < bb || (ob == bb && oi < bi)) { bb = ob; bi = oi; }
        }
        best[j] = bb; bidx[j] = bi;
    }
    if (lane == 0) {
        double lp = 0.0;
        #pragma unroll
        for (int j = 0; j < 8; ++j) {
            const int n = n0 + w * 8 + j;
            out_idx[n] = (float)bidx[j];
            idx_i[n] = bidx[j];
            lp += (double)best[j];
        }
        atomicAdd(loss_acc, lp);
    }
}

// ================== shared epilogue kernels ==================
__global__ __launch_bounds__(256) void gather_kernel(const float* __restrict__ emb,
                                                     const int* __restrict__ idx_i,
                                                     float* __restrict__ zq) {
    const int blk = blockIdx.x;
    const int b = blk >> 4;
    const int t0 = (blk & 15) * 64;
    const int q = threadIdx.x & 63;
    const int dc = threadIdx.x >> 6;
    const int n = b * TT + t0 + q;
    const int k = idx_i[n];
    const f4* erow = (const f4*)(emb + (size_t)k * DD + dc * 64);
    #pragma unroll
    for (int jj = 0; jj < 16; ++jj) {
        const f4 v = erow[jj];
        const int d = dc * 64 + jj * 4;
        zq[(size_t)(b * DD + d + 0) * TT + t0 + q] = v.x;
        zq[(size_t)(b * DD + d + 1) * TT + t0 + q] = v.y;
        zq[(size_t)(b * DD + d + 2) * TT + t0 + q] = v.z;
        zq[(size_t)(b * DD + d + 3) * TT + t0 + q] = v.w;
    }
}

__global__ void fin_kernel(const double* __restrict__ loss_acc,
                           float* __restrict__ out_loss) {
    out_loss[0] = (float)(loss_acc[0] * (1.0 / ((double)BB * DD * TT)));
}

extern "C" void kernel_launch(void* const* d_in, const int* in_sizes, int n_in,
                              void* d_out, int out_size, void* d_ws, size_t ws_size,
                              hipStream_t stream) {
    const float* z_e = (const float*)d_in[0];
    const float* emb = (const float*)d_in[1];

    float* out      = (float*)d_out;
    float* zq       = out;
    float* out_loss = out + (size_t)BB * DD * TT;
    float* out_idx  = out_loss + 1;

    char* ws = (char*)d_ws;
    double* loss_acc = (double*)(ws + WS_LOSS);
    float*  Bf       = (float*)(ws + WS_BF);
    float*  Af       = (float*)(ws + WS_AF);
    int*    idx_i    = (int*)(ws + WS_IDX);

    hipMemsetAsync(d_ws, 0, 1088, stream);
    bsum_kernel<<<KK / 256, 256, 0, stream>>>(emb, Bf);

    if (ws_size >= (size_t)WS_NEED) {
        int*    cnt    = (int*)(ws + WS_CNT);
        int*    bcnt   = (int*)(ws + WS_BCNT);
        unsigned long long* winner = (unsigned long long*)(ws + WS_WIN);
        float*  zt     = (float*)(ws + WS_ZT);
        float*  tmp_min = (float*)(ws + WS_TMIN);
        int*    bucket = (int*)(ws + WS_BKT);
        int*    list   = (int*)(ws + WS_LIST);
        unsigned short* zf = (unsigned short*)(ws + WS_ZF);
        unsigned short* ef = (unsigned short*)(ws + WS_EF);

        fusedz_kernel<<<(BB * TT) / 64, 256, 0, stream>>>(z_e, zt, zf, Af);
        convef_kernel<<<(KK * DD) / 1024, 256, 0, stream>>>(emb, ef);
        mfma1_kernel<<<(BB * TT / 128) * 8, 512, 0, stream>>>(zf, ef, Af, Bf, tmp_min);
        select_kernel<<<(BB * TT) / 4, 256, 0, stream>>>(tmp_min, bcnt, bucket, list, cnt, winner);
        rescan_bucket_kernel<<<256, 256, 0, stream>>>(zt, emb, Af, Bf, bcnt, bucket, winner);
        rescan2_kernel<<<128, 256, 0, stream>>>(zt, emb, Af, Bf, list, cnt, winner);
        final_kernel<<<(BB * TT) / 256, 256, 0, stream>>>(winner, out_idx, idx_i, loss_acc);
    } else {
        asum_kernel<<<(BB * TT) / 256, 256, 0, stream>>>(z_e, Af);
        score5_kernel<<<(BB * TT) / 32, 256, 0, stream>>>(z_e, emb, Bf, Af, out_idx, idx_i, loss_acc);
    }

    gather_kernel<<<(BB * TT) / 64, 256, 0, stream>>>(emb, idx_i, zq);
    fin_kernel<<<1, 1, 0, stream>>>(loss_acc, out_loss);
}

// Round 3
// 535.459 us; speedup vs baseline: 1.3733x; 1.3733x over previous
//
#include <hip/hip_runtime.h>
#include <stdint.h>

#define BB 32
#define DD 256
#define TT 1024
#define KK 8192

typedef __attribute__((ext_vector_type(2))) float f2;
typedef __attribute__((ext_vector_type(4))) float f4;
typedef __attribute__((ext_vector_type(8))) _Float16 hfrag;   // 8 f16 = 4 VGPR
typedef __attribute__((ext_vector_type(16))) float f16acc;    // 32x32 MFMA acc

#if __has_builtin(__builtin_elementwise_fma)
#define PKFMA(a, b, c) __builtin_elementwise_fma(a, b, c)
#else
static __device__ __forceinline__ f2 pkfma_(f2 a, f2 b, f2 c) {
    f2 r; r.x = __fmaf_rn(a.x, b.x, c.x); r.y = __fmaf_rn(a.y, b.y, c.y); return r;
}
#define PKFMA(a, b, c) pkfma_(a, b, c)
#endif

#define GLD16(gp, lp)                                                          \
    __builtin_amdgcn_global_load_lds(                                          \
        (const __attribute__((address_space(1))) uint32_t*)(gp),               \
        (__attribute__((address_space(3))) uint32_t*)(lp), 16, 0, 0)

#define MU 3.0e-4f
#define BCAP 4096
#define LIST_CAP 1048576
// e is pre-scaled by 1024 before fp16 cast; dist = Af+Bf - 2*dot/1024
#define INV512 0.001953125f

// ---------------- fast-path ws layout (bytes) ----------------
#define WS_LOSS   0            // double
#define WS_CNT    8            // int (overflow count)
#define WS_BCNT   16           // int[256]
#define WS_BF     1088
#define WS_AF     33856
#define WS_IDX    164928
#define WS_WIN    296000
#define WS_ZT     558144
#define WS_TMIN   34112576
#define WS_BKT    67667008
#define WS_LIST   71861312
#define WS_ZF     76055616     // fp16 z   [32768][256] = 16.8 MB
#define WS_EF     92832832     // fp16 e*1024 [8192][256] = 4.2 MB
#define WS_NEED   97027136

__device__ __forceinline__ unsigned short h16(float x) {
    _Float16 t = (_Float16)x;                    // RNE
    return __builtin_bit_cast(unsigned short, t);
}

// Bit-exact numpy pairwise_sum of x[i]^2, n=256.
__device__ __forceinline__ float np_sq_sum256(const float* __restrict__ base, int stride) {
    float res[2];
    #pragma unroll
    for (int blk = 0; blk < 2; ++blk) {
        const int o = blk * 128;
        float r[8];
        #pragma unroll
        for (int j = 0; j < 8; ++j) {
            const float x = base[(o + j) * stride];
            r[j] = __fmul_rn(x, x);
        }
        for (int i = 8; i < 128; i += 8) {
            #pragma unroll
            for (int j = 0; j < 8; ++j) {
                const float x = base[(o + i + j) * stride];
                r[j] = __fadd_rn(r[j], __fmul_rn(x, x));
            }
        }
        res[blk] = __fadd_rn(__fadd_rn(__fadd_rn(r[0], r[1]), __fadd_rn(r[2], r[3])),
                             __fadd_rn(__fadd_rn(r[4], r[5]), __fadd_rn(r[6], r[7])));
    }
    return __fadd_rn(res[0], res[1]);
}

__global__ __launch_bounds__(256) void bsum_kernel(const float* __restrict__ emb,
                                                   float* __restrict__ Bf) {
    const int k = blockIdx.x * 256 + threadIdx.x;
    Bf[k] = np_sq_sum256(emb + (size_t)k * DD, 1);
}

__global__ __launch_bounds__(256) void asum_kernel(const float* __restrict__ z_e,
                                                   float* __restrict__ Af) {
    const int n = blockIdx.x * 256 + threadIdx.x;
    const int b = n >> 10, t = n & 1023;
    Af[n] = np_sq_sum256(z_e + ((size_t)b << 18) + t, TT);
}

// ---- fused z prep: zt (fp32 [q][d]) + zf (fp16) + Af, one pass ----
__global__ __launch_bounds__(256) void fusedz_kernel(const float* __restrict__ z_e,
                                                     float* __restrict__ zt,
                                                     unsigned short* __restrict__ zf,
                                                     float* __restrict__ Af) {
    __shared__ float tile[64 * 261];
    const int tid = threadIdx.x, l = tid & 63, r = tid >> 6;
    const int n0 = blockIdx.x * 64;           // 512 blocks
    const int b = n0 >> 10, t0 = n0 & 1023;
    for (int d = r; d < DD; d += 4)
        tile[l * 261 + d] = z_e[(size_t)(b * DD + d) * TT + t0 + l];
    __syncthreads();
    const int q = tid >> 2, c0 = (tid & 3) * 64;
    const float* src = &tile[q * 261 + c0];
    float* dzt = zt + (size_t)(n0 + q) * DD + c0;
    unsigned short* dzf = zf + (size_t)(n0 + q) * DD + c0;
    #pragma unroll
    for (int i = 0; i < 16; ++i) {
        f4 v;
        v.x = src[4 * i + 0]; v.y = src[4 * i + 1];
        v.z = src[4 * i + 2]; v.w = src[4 * i + 3];
        *(f4*)(dzt + 4 * i) = v;
        ushort4 h;
        h.x = h16(v.x); h.y = h16(v.y); h.z = h16(v.z); h.w = h16(v.w);
        *(ushort4*)(dzf + 4 * i) = h;
    }
    if (tid < 64) Af[n0 + tid] = np_sq_sum256(&tile[tid * 261], 1);
}

// ---- e -> fp16, scaled by 1024 (exact pow2) to stay in fp16 normal range ----
__global__ __launch_bounds__(256) void convef_kernel(const float* __restrict__ emb,
                                                     unsigned short* __restrict__ ef) {
    const int i0 = (blockIdx.x * 256 + threadIdx.x) * 4;
    const f4 v = *(const f4*)(emb + i0);
    ushort4 h;
    h.x = h16(v.x * 1024.0f); h.y = h16(v.y * 1024.0f);
    h.z = h16(v.z * 1024.0f); h.w = h16(v.w * 1024.0f);
    *(ushort4*)(ef + i0) = h;
}

// ---- K1: fp16 32x32x16 MFMA scorer, operand-swapped (C: row=code, col=q) ----
// Grid 4096 = 256 qt x 16 kb. Block = 128 q x 512 codes (4 tiles of 128),
// 256 thr = 4 waves, wave = 64q x 64codes per tile. z resident in VGPR
// (128 regs, loaded once, reused 4 tiles); e-tile 64KB single-buffer LDS in
// fragment order (conflict-free ds_read_b128); stage of tile kt+1 issued in
// epilogue's shadow. Operand swap makes the 32-code-group min a per-lane
// 15-fmin reg tree + one shfl_xor(32). minbuf stride 17 -> conflict-free;
// one coalesced full-line tmp_min write per block.
__device__ __forceinline__ void epi32(const f16acc acc, const float* BfLp,
                                      float (*minbuf)[17], int bfbase, int qrow,
                                      int col, float afv, int lane) {
    const f4 b0 = *(const f4*)&BfLp[bfbase];
    const f4 b1 = *(const f4*)&BfLp[bfbase + 8];
    const f4 b2 = *(const f4*)&BfLp[bfbase + 16];
    const f4 b3 = *(const f4*)&BfLp[bfbase + 24];
    float m =    __fmaf_rn(acc[0],  -INV512, b0.x);
    m = fminf(m, __fmaf_rn(acc[1],  -INV512, b0.y));
    m = fminf(m, __fmaf_rn(acc[2],  -INV512, b0.z));
    m = fminf(m, __fmaf_rn(acc[3],  -INV512, b0.w));
    m = fminf(m, __fmaf_rn(acc[4],  -INV512, b1.x));
    m = fminf(m, __fmaf_rn(acc[5],  -INV512, b1.y));
    m = fminf(m, __fmaf_rn(acc[6],  -INV512, b1.z));
    m = fminf(m, __fmaf_rn(acc[7],  -INV512, b1.w));
    m = fminf(m, __fmaf_rn(acc[8],  -INV512, b2.x));
    m = fminf(m, __fmaf_rn(acc[9],  -INV512, b2.y));
    m = fminf(m, __fmaf_rn(acc[10], -INV512, b2.z));
    m = fminf(m, __fmaf_rn(acc[11], -INV512, b2.w));
    m = fminf(m, __fmaf_rn(acc[12], -INV512, b3.x));
    m = fminf(m, __fmaf_rn(acc[13], -INV512, b3.y));
    m = fminf(m, __fmaf_rn(acc[14], -INV512, b3.z));
    m = fminf(m, __fmaf_rn(acc[15], -INV512, b3.w));
    m = fminf(m, __shfl_xor(m, 32));
    if (lane < 32) minbuf[qrow][col] = afv + m;
}

__global__ __launch_bounds__(256, 2) void mfma1_kernel(
    const unsigned short* __restrict__ zf, const unsigned short* __restrict__ ef,
    const float* __restrict__ Af, const float* __restrict__ Bf,
    float* __restrict__ tmp_min) {
    __shared__ unsigned short Bb[32768];   // 64 KiB: [rg4][ks16][lane64][8 f16]
    __shared__ float minbuf[128][17];      // 8.5 KiB, stride 17 conflict-free
    __shared__ float BfL[512];             // 2 KiB

    const int tid  = threadIdx.x;
    const int lane = tid & 63;
    const int w    = tid >> 6;         // 0..3
    const int l31  = lane & 31;
    const int hf   = lane >> 5;        // 0/1
    const int wq   = w & 1;            // q-half (64 rows)
    const int wk   = w >> 1;           // code-half of tile (rg pair)
    const int qt   = blockIdx.x >> 4;  // 256 q-tiles of 128
    const int kb   = blockIdx.x & 15;  // 16 k-slabs of 512 codes

    BfL[tid]       = Bf[kb * 512 + tid];
    BfL[tid + 256] = Bf[kb * 512 + 256 + tid];

    // ---- z resident in registers: B-operand frags (col=q), 128 VGPR ----
    hfrag zr[2][16];
    {
        const unsigned short* zb =
            zf + (size_t)(qt * 128 + wq * 64 + l31) * DD + hf * 8;
        #pragma unroll
        for (int cg = 0; cg < 2; ++cg)
            #pragma unroll
            for (int ks = 0; ks < 16; ++ks)
                zr[cg][ks] = *(const hfrag*)(zb + (size_t)cg * 32 * DD + ks * 16);
    }
    const float af0 = Af[qt * 128 + wq * 64 + l31];
    const float af1 = Af[qt * 128 + wq * 64 + 32 + l31];

    // ---- stage e tile 0: wave w stages code-group w (fragment order) ----
    const unsigned short* esrc =
        ef + (size_t)(kb * 512 + w * 32 + l31) * DD + hf * 8;
    #pragma unroll
    for (int ks = 0; ks < 16; ++ks)
        GLD16(esrc + ks * 16, Bb + (w * 16 + ks) * 512);
    __syncthreads();

    for (int kt = 0; kt < 4; ++kt) {
        f16acc acc00 = {}, acc01 = {}, acc10 = {}, acc11 = {};
        #pragma unroll
        for (int ks = 0; ks < 16; ++ks) {
            const hfrag e0 = *(const hfrag*)(Bb + ((wk * 2 + 0) * 16 + ks) * 512 + lane * 8);
            const hfrag e1 = *(const hfrag*)(Bb + ((wk * 2 + 1) * 16 + ks) * 512 + lane * 8);
            acc00 = __builtin_amdgcn_mfma_f32_32x32x16_f16(e0, zr[0][ks], acc00, 0, 0, 0);
            acc01 = __builtin_amdgcn_mfma_f32_32x32x16_f16(e0, zr[1][ks], acc01, 0, 0, 0);
            acc10 = __builtin_amdgcn_mfma_f32_32x32x16_f16(e1, zr[0][ks], acc10, 0, 0, 0);
            acc11 = __builtin_amdgcn_mfma_f32_32x32x16_f16(e1, zr[1][ks], acc11, 0, 0, 0);
        }
        __syncthreads();                       // all waves done reading Bb
        if (kt < 3) {                          // stage next tile (shadowed by epilogue)
            const unsigned short* esn = esrc + (size_t)(kt + 1) * 128 * DD;
            #pragma unroll
            for (int ks = 0; ks < 16; ++ks)
                GLD16(esn + ks * 16, Bb + (w * 16 + ks) * 512);
        }
        {   // epilogue: per-(q, 32-code-group) min into minbuf
            const int bfb0 = kt * 128 + (wk * 2 + 0) * 32 + hf * 4;
            const int bfb1 = kt * 128 + (wk * 2 + 1) * 32 + hf * 4;
            const int qr0 = wq * 64 + l31, qr1 = wq * 64 + 32 + l31;
            const int c0 = kt * 4 + wk * 2, c1 = c0 + 1;
            epi32(acc00, BfL, minbuf, bfb0, qr0, c0, af0, lane);
            epi32(acc01, BfL, minbuf, bfb0, qr1, c0, af1, lane);
            epi32(acc10, BfL, minbuf, bfb1, qr0, c1, af0, lane);
            epi32(acc11, BfL, minbuf, bfb1, qr1, c1, af1, lane);
        }
        if (kt < 3) __syncthreads();           // drains vmcnt -> next tile ready
    }
    __syncthreads();
    // coalesced tmp_min write: 128 rows x 16 groups, full 64B line per row
    {
        const int qloc = tid >> 1, h8 = (tid & 1) * 8;
        const float* mrow = &minbuf[qloc][h8];
        f4 v0, v1;
        v0.x = mrow[0]; v0.y = mrow[1]; v0.z = mrow[2]; v0.w = mrow[3];
        v1.x = mrow[4]; v1.y = mrow[5]; v1.z = mrow[6]; v1.w = mrow[7];
        float* dst = tmp_min + (size_t)(qt * 128 + qloc) * 256 + kb * 16 + h8;
        *(f4*)dst       = v0;
        *(f4*)(dst + 4) = v1;
    }
}

// ---- K2: fused select: per-q min+thr, winner init, bucket scatter ----
__global__ __launch_bounds__(256) void select_kernel(
    const float* __restrict__ tmp_min, int* __restrict__ bcnt,
    int* __restrict__ bucket, int* __restrict__ list, int* __restrict__ cnt,
    unsigned long long* __restrict__ winner) {
    const int tid = threadIdx.x, lane = tid & 63, w = tid >> 6;
    const int q = blockIdx.x * 4 + w;          // 8192 blocks
    const f4 v = *(const f4*)(tmp_min + (size_t)q * 256 + lane * 4);
    float m = fminf(fminf(v.x, v.y), fminf(v.z, v.w));
    #pragma unroll
    for (int off = 1; off < 64; off <<= 1) m = fminf(m, __shfl_xor(m, off));
    const float thr = m + MU;
    if (lane == 0) winner[q] = ~0ULL;
    float vv[4] = {v.x, v.y, v.z, v.w};
    #pragma unroll
    for (int j = 0; j < 4; ++j) {
        if (vv[j] <= thr) {
            const int g = lane * 4 + j;
            const int pos = atomicAdd(&bcnt[g], 1);
            if (pos < BCAP) bucket[g * BCAP + pos] = q;
            else {
                const int op = atomicAdd(cnt, 1);
                if (op < LIST_CAP) list[op] = (q << 8) | g;
            }
        }
    }
}

// ---- K3: bucketed exact re-rank: block per 32-code group, e staged once ----
__global__ __launch_bounds__(256) void rescan_bucket_kernel(
    const float* __restrict__ zt, const float* __restrict__ emb,
    const float* __restrict__ Af, const float* __restrict__ Bf,
    const int* __restrict__ bcnt, const int* __restrict__ bucket,
    unsigned long long* __restrict__ winner) {
    __shared__ float elds[256 * 33];   // [d][k], stride 33 -> conflict-free
    __shared__ float zbuf[8][256];
    __shared__ float bfs[32];
    const int g = blockIdx.x;          // 256 groups
    const int tid = threadIdx.x, lane = tid & 63, w = tid >> 6;
    const int half = lane >> 5, l32 = lane & 31, slot = w * 2 + half;
    {   // stage e rows (coalesced reads, transpose into [d][k])
        const int k = tid >> 3, s0 = (tid & 7) * 32;
        const float* src = emb + (size_t)(g * 32 + k) * DD + s0;
        #pragma unroll
        for (int i = 0; i < 8; ++i) {
            const f4 v = *(const f4*)(src + i * 4);
            elds[(s0 + 4 * i + 0) * 33 + k] = v.x;
            elds[(s0 + 4 * i + 1) * 33 + k] = v.y;
            elds[(s0 + 4 * i + 2) * 33 + k] = v.z;
            elds[(s0 + 4 * i + 3) * 33 + k] = v.w;
        }
        if (tid < 32) bfs[tid] = Bf[g * 32 + tid];
    }
    __syncthreads();
    const int nit = min(bcnt[g], BCAP);
    const int kme = g * 32 + l32;
    for (int base = 0; base < nit; base += 8) {
        const int it = base + slot;
        int q = -1;
        if (it < nit) {
            q = bucket[g * BCAP + it];
            f4* zb = (f4*)&zbuf[slot][0];
            const f4* zsrc = (const f4*)(zt + (size_t)q * DD);
            zb[l32]      = zsrc[l32];
            zb[l32 + 32] = zsrc[l32 + 32];
        }
        __syncthreads();
        if (it < nit) {
            const float* zp = &zbuf[slot][0];
            float c = 0.0f;
            #pragma unroll 8
            for (int d = 0; d < DD; ++d)
                c = __fmaf_rn(zp[d], elds[d * 33 + l32], c);
            float bv = __fsub_rn(__fadd_rn(Af[q], bfs[l32]), __fadd_rn(c, c));
            int bk = kme;
            #pragma unroll
            for (int off = 1; off < 32; off <<= 1) {
                const float ob = __shfl_xor(bv, off);
                const int   ok = __shfl_xor(bk, off);
                if (ob < bv || (ob == bv && ok < bk)) { bv = ob; bk = ok; }
            }
            if (l32 == 0)
                atomicMin(winner + q,
                          (((unsigned long long)__float_as_uint(bv)) << 32) | (unsigned)bk);
        }
        __syncthreads();
    }
}

// ---- K3x: overflow re-rank (per-item, rare) ----
__global__ __launch_bounds__(256) void rescan2_kernel(
    const float* __restrict__ zt, const float* __restrict__ emb,
    const float* __restrict__ Af, const float* __restrict__ Bf,
    const int* __restrict__ list, const int* __restrict__ cnt,
    unsigned long long* __restrict__ winner) {
    __shared__ float zbuf[8][256];
    const int tid = threadIdx.x, lane = tid & 63, w = tid >> 6;
    const int half = lane >> 5, l32 = lane & 31;
    const int slot = blockIdx.x * 8 + w * 2 + half;
    const int slots = gridDim.x * 8;
    const int n = min(*cnt, LIST_CAP);
    f4* zb = (f4*)&zbuf[w * 2 + half][0];
    for (int it = slot; it < n; it += slots) {
        const int id = list[it];
        const int q = id >> 8, g = id & 255;
        const f4* zsrc = (const f4*)(zt + (size_t)q * DD);
        zb[l32]      = zsrc[l32];
        zb[l32 + 32] = zsrc[l32 + 32];
        const int k = g * 32 + l32;
        const f4* e = (const f4*)(emb + (size_t)k * DD);
        float c = 0.0f;
        #pragma unroll 8
        for (int i = 0; i < 64; ++i) {
            const f4 ev = e[i];
            const f4 zv = zb[i];
            c = __fmaf_rn(zv.x, ev.x, c);
            c = __fmaf_rn(zv.y, ev.y, c);
            c = __fmaf_rn(zv.z, ev.z, c);
            c = __fmaf_rn(zv.w, ev.w, c);
        }
        float bv = __fsub_rn(__fadd_rn(Af[q], Bf[k]), __fadd_rn(c, c));
        int bk = k;
        #pragma unroll
        for (int off = 1; off < 32; off <<= 1) {
            const float ob = __shfl_xor(bv, off);
            const int   ok = __shfl_xor(bk, off);
            if (ob < bv || (ob == bv && ok < bk)) { bv = ob; bk = ok; }
        }
        if (l32 == 0)
            atomicMin(winner + q,
                      (((unsigned long long)__float_as_uint(bv)) << 32) | (unsigned)bk);
    }
}

// ---- K4: finalize idx + loss ----
__global__ __launch_bounds__(256) void final_kernel(
    const unsigned long long* __restrict__ winner, float* __restrict__ out_idx,
    int* __restrict__ idx_i, double* __restrict__ loss_acc) {
    __shared__ double ls[4];
    const int tid = threadIdx.x, lane = tid & 63, w = tid >> 6;
    const int q = blockIdx.x * 256 + tid;
    const unsigned long long wv = winner[q];
    const int k = (int)(wv & 0xFFFFFFFFu);
    idx_i[q] = k;
    out_idx[q] = (float)k;
    double s = (double)__uint_as_float((unsigned)(wv >> 32));
    #pragma unroll
    for (int off = 1; off < 64; off <<= 1) s += __shfl_xor(s, off);
    if (lane == 0) ls[w] = s;
    __syncthreads();
    if (tid == 0) atomicAdd(loss_acc, ls[0] + ls[1] + ls[2] + ls[3]);
}

// ================== r5 fallback scorer (ws too small) ==================
__device__ __forceinline__ void ldstage(const float* __restrict__ emb, int st,
                                        int c, int p, f4* g) {
    const int kt = st >> 4, dc = st & 15;
    const float* src = emb + (((size_t)(kt * 512 + p * 128 + c)) << 8) + dc * 16;
    #pragma unroll
    for (int m = 0; m < 4; ++m) g[m] = *(const f4*)(src + 4 * m);
    const float* src2 = src + (64 << 8);
    #pragma unroll
    for (int m = 0; m < 4; ++m) g[4 + m] = *(const f4*)(src2 + 4 * m);
}

__global__ __launch_bounds__(256, 2) void score5_kernel(
    const float* __restrict__ z_e, const float* __restrict__ emb,
    const float* __restrict__ Bf, const float* __restrict__ Af,
    float* __restrict__ out_idx, int* __restrict__ idx_i,
    double* __restrict__ loss_acc) {
    __shared__ float zl[32 * 260];
    __shared__ float etp[64 * 132];
    const int tid = threadIdx.x;
    const int lane = tid & 63;
    const int w = tid >> 6;
    const int n0 = blockIdx.x * 32;
    const int b = n0 >> 10, t0 = n0 & 1023;
    {
        const int q = tid & 31;
        for (int d = tid >> 5; d < DD; d += 8)
            zl[q * 260 + d] = z_e[((size_t)(b * DD + d) << 10) + t0 + q];
    }
    float Aq[8];
    #pragma unroll
    for (int j = 0; j < 8; ++j) Aq[j] = Af[n0 + w * 8 + j];
    float best[8];
    int bidx[8];
    #pragma unroll
    for (int j = 0; j < 8; ++j) { best[j] = 3.0e38f; bidx[j] = 0; }
    f4 g[8];
    ldstage(emb, 0, lane, w, g);
    for (int kt = 0; kt < 16; ++kt) {
        f2 acc[8][4];
        #pragma unroll
        for (int j = 0; j < 8; ++j)
            #pragma unroll
            for (int p2 = 0; p2 < 4; ++p2) acc[j][p2] = (f2){0.0f, 0.0f};
        for (int dc = 0; dc < 16; ++dc) {
            __syncthreads();
            {
                float* dst = etp + lane * 132 + w * 32;
                #pragma unroll
                for (int m = 0; m < 4; ++m) {
                    const f4 a = g[m], bv = g[4 + m];
                    *(f4*)(dst + 8 * m)     = __builtin_shufflevector(a, bv, 0, 4, 1, 5);
                    *(f4*)(dst + 8 * m + 4) = __builtin_shufflevector(a, bv, 2, 6, 3, 7);
                }
            }
            __syncthreads();
            const int st = kt * 16 + dc;
            ldstage(emb, st < 255 ? st + 1 : 255, lane, w, g);
            #pragma unroll
            for (int s4 = 0; s4 < 4; ++s4) {
                const int dd0 = s4 * 4;
                f4 zv[8];
                #pragma unroll
                for (int j = 0; j < 8; ++j)
                    zv[j] = *(const f4*)(zl + (w * 8 + j) * 260 + dc * 16 + dd0);
                f4 ev[4][2];
                #pragma unroll
                for (int p2 = 0; p2 < 4; ++p2) {
                    const float* eb = etp + lane * 132 + p2 * 32 + dd0 * 2;
                    ev[p2][0] = *(const f4*)(eb);
                    ev[p2][1] = *(const f4*)(eb + 4);
                }
                #pragma unroll
                for (int j = 0; j < 8; ++j) {
                    #pragma unroll
                    for (int dd = 0; dd < 4; ++dd) {
                        const float zs = zv[j][dd];
                        const f2 z2 = {zs, zs};
                        #pragma unroll
                        for (int p2 = 0; p2 < 4; ++p2) {
                            const f4 evv = ev[p2][dd >> 1];
                            const f2 e2 = (dd & 1)
                                ? __builtin_shufflevector(evv, evv, 2, 3)
                                : __builtin_shufflevector(evv, evv, 0, 1);
                            acc[j][p2] = PKFMA(z2, e2, acc[j][p2]);
                        }
                    }
                }
            }
        }
        const int kt0 = kt * 512;
        float Bk[8];
        #pragma unroll
        for (int i = 0; i < 8; ++i) Bk[i] = Bf[kt0 + 64 * i + lane];
        #pragma unroll
        for (int p2 = 0; p2 < 4; ++p2) {
            #pragma unroll
            for (int s = 0; s < 2; ++s) {
                const int i = 2 * p2 + s;
                #pragma unroll
                for (int j = 0; j < 8; ++j) {
                    const float C = s ? acc[j][p2].y : acc[j][p2].x;
                    const float dist = __fsub_rn(__fadd_rn(Aq[j], Bk[i]), __fadd_rn(C, C));
                    const int k = kt0 + 64 * i + lane;
                    if (dist < best[j]) { best[j] = dist; bidx[j] = k; }
                }
            }
        }
    }
    #pragma unroll
    for (int j = 0; j < 8; ++j) {
        float bb = best[j];
        int bi = bidx[j];
        #pragma unroll
        for (int off = 1; off < 64; off <<= 1) {
            const float ob = __shfl_xor(bb, off);
            const int oi = __shfl_xor(bi, off);
            if (ob < bb || (ob == bb && oi < bi)) { bb = ob; bi = oi; }
        }
        best[j] = bb; bidx[j] = bi;
    }
    if (lane == 0) {
        double lp = 0.0;
        #pragma unroll
        for (int j = 0; j < 8; ++j) {
            const int n = n0 + w * 8 + j;
            out_idx[n] = (float)bidx[j];
            idx_i[n] = bidx[j];
            lp += (double)best[j];
        }
        atomicAdd(loss_acc, lp);
    }
}

// ================== shared epilogue kernels ==================
__global__ __launch_bounds__(256) void gather_kernel(const float* __restrict__ emb,
                                                     const int* __restrict__ idx_i,
                                                     float* __restrict__ zq) {
    const int blk = blockIdx.x;
    const int b = blk >> 4;
    const int t0 = (blk & 15) * 64;
    const int q = threadIdx.x & 63;
    const int dc = threadIdx.x >> 6;
    const int n = b * TT + t0 + q;
    const int k = idx_i[n];
    const f4* erow = (const f4*)(emb + (size_t)k * DD + dc * 64);
    #pragma unroll
    for (int jj = 0; jj < 16; ++jj) {
        const f4 v = erow[jj];
        const int d = dc * 64 + jj * 4;
        zq[(size_t)(b * DD + d + 0) * TT + t0 + q] = v.x;
        zq[(size_t)(b * DD + d + 1) * TT + t0 + q] = v.y;
        zq[(size_t)(b * DD + d + 2) * TT + t0 + q] = v.z;
        zq[(size_t)(b * DD + d + 3) * TT + t0 + q] = v.w;
    }
}

__global__ void fin_kernel(const double* __restrict__ loss_acc,
                           float* __restrict__ out_loss) {
    out_loss[0] = (float)(loss_acc[0] * (1.0 / ((double)BB * DD * TT)));
}

extern "C" void kernel_launch(void* const* d_in, const int* in_sizes, int n_in,
                              void* d_out, int out_size, void* d_ws, size_t ws_size,
                              hipStream_t stream) {
    const float* z_e = (const float*)d_in[0];
    const float* emb = (const float*)d_in[1];

    float* out      = (float*)d_out;
    float* zq       = out;
    float* out_loss = out + (size_t)BB * DD * TT;
    float* out_idx  = out_loss + 1;

    char* ws = (char*)d_ws;
    double* loss_acc = (double*)(ws + WS_LOSS);
    float*  Bf       = (float*)(ws + WS_BF);
    float*  Af       = (float*)(ws + WS_AF);
    int*    idx_i    = (int*)(ws + WS_IDX);

    hipMemsetAsync(d_ws, 0, 1088, stream);
    bsum_kernel<<<KK / 256, 256, 0, stream>>>(emb, Bf);

    if (ws_size >= (size_t)WS_NEED) {
        int*    cnt    = (int*)(ws + WS_CNT);
        int*    bcnt   = (int*)(ws + WS_BCNT);
        unsigned long long* winner = (unsigned long long*)(ws + WS_WIN);
        float*  zt     = (float*)(ws + WS_ZT);
        float*  tmp_min = (float*)(ws + WS_TMIN);
        int*    bucket = (int*)(ws + WS_BKT);
        int*    list   = (int*)(ws + WS_LIST);
        unsigned short* zf = (unsigned short*)(ws + WS_ZF);
        unsigned short* ef = (unsigned short*)(ws + WS_EF);

        fusedz_kernel<<<(BB * TT) / 64, 256, 0, stream>>>(z_e, zt, zf, Af);
        convef_kernel<<<(KK * DD) / 1024, 256, 0, stream>>>(emb, ef);
        mfma1_kernel<<<(BB * TT / 128) * 16, 256, 0, stream>>>(zf, ef, Af, Bf, tmp_min);
        select_kernel<<<(BB * TT) / 4, 256, 0, stream>>>(tmp_min, bcnt, bucket, list, cnt, winner);
        rescan_bucket_kernel<<<256, 256, 0, stream>>>(zt, emb, Af, Bf, bcnt, bucket, winner);
        rescan2_kernel<<<128, 256, 0, stream>>>(zt, emb, Af, Bf, list, cnt, winner);
        final_kernel<<<(BB * TT) / 256, 256, 0, stream>>>(winner, out_idx, idx_i, loss_acc);
    } else {
        asum_kernel<<<(BB * TT) / 256, 256, 0, stream>>>(z_e, Af);
        score5_kernel<<<(BB * TT) / 32, 256, 0, stream>>>(z_e, emb, Bf, Af, out_idx, idx_i, loss_acc);
    }

    gather_kernel<<<(BB * TT) / 64, 256, 0, stream>>>(emb, idx_i, zq);
    fin_kernel<<<1, 1, 0, stream>>>(loss_acc, out_loss);
}

// Round 4
// 467.654 us; speedup vs baseline: 1.5725x; 1.1450x over previous
//
#include <hip/hip_runtime.h>
#include <stdint.h>

#define BB 32
#define DD 256
#define TT 1024
#define KK 8192

typedef __attribute__((ext_vector_type(2))) float f2;
typedef __attribute__((ext_vector_type(4))) float f4;
typedef __attribute__((ext_vector_type(8))) _Float16 hfrag;   // 8 f16 = 4 VGPR
typedef __attribute__((ext_vector_type(16))) float f16acc;    // 32x32 MFMA acc

#if __has_builtin(__builtin_elementwise_fma)
#define PKFMA(a, b, c) __builtin_elementwise_fma(a, b, c)
#else
static __device__ __forceinline__ f2 pkfma_(f2 a, f2 b, f2 c) {
    f2 r; r.x = __fmaf_rn(a.x, b.x, c.x); r.y = __fmaf_rn(a.y, b.y, c.y); return r;
}
#define PKFMA(a, b, c) pkfma_(a, b, c)
#endif

#define GLD16(gp, lp)                                                          \
    __builtin_amdgcn_global_load_lds(                                          \
        (const __attribute__((address_space(1))) uint32_t*)(gp),               \
        (__attribute__((address_space(3))) uint32_t*)(lp), 16, 0, 0)

#define MU 3.0e-4f
#define BCAP 4096
#define LIST_CAP 1048576
// e is pre-scaled by 1024 before fp16 cast; dist = Af+Bf - 2*dot/1024
#define INV512 0.001953125f

// fragment-order layout for fp16 operands (both zf and ef):
//   slot(g, ks, lane) at short-offset ((g*16 + ks)*64 + lane)*8
//   holds row g*32 + (lane&31), cols ks*16 + (lane>>5)*8 .. +8
// -> every wave-level 16B/lane access (GLD16 staging, zr prologue) is one
//    contiguous 1KB burst (m173 pre-swizzled-source pattern).

// ---------------- fast-path ws layout (bytes) ----------------
#define WS_LOSS   0            // double
#define WS_CNT    8            // int (overflow count)
#define WS_BCNT   16           // int[256]
#define WS_BF     1088
#define WS_AF     33856
#define WS_IDX    164928
#define WS_WIN    296000
#define WS_ZT     558144
#define WS_TMIN   34112576
#define WS_BKT    67667008
#define WS_LIST   71861312
#define WS_ZF     76055616     // fp16 z  frag-order, 16.8 MB
#define WS_EF     92832832     // fp16 e*1024 frag-order, 4.2 MB
#define WS_NEED   97027136

__device__ __forceinline__ unsigned short h16(float x) {
    _Float16 t = (_Float16)x;                    // RNE
    return __builtin_bit_cast(unsigned short, t);
}

// Bit-exact numpy pairwise_sum of x[i]^2, n=256.
__device__ __forceinline__ float np_sq_sum256(const float* __restrict__ base, int stride) {
    float res[2];
    #pragma unroll
    for (int blk = 0; blk < 2; ++blk) {
        const int o = blk * 128;
        float r[8];
        #pragma unroll
        for (int j = 0; j < 8; ++j) {
            const float x = base[(o + j) * stride];
            r[j] = __fmul_rn(x, x);
        }
        for (int i = 8; i < 128; i += 8) {
            #pragma unroll
            for (int j = 0; j < 8; ++j) {
                const float x = base[(o + i + j) * stride];
                r[j] = __fadd_rn(r[j], __fmul_rn(x, x));
            }
        }
        res[blk] = __fadd_rn(__fadd_rn(__fadd_rn(r[0], r[1]), __fadd_rn(r[2], r[3])),
                             __fadd_rn(__fadd_rn(r[4], r[5]), __fadd_rn(r[6], r[7])));
    }
    return __fadd_rn(res[0], res[1]);
}

__global__ __launch_bounds__(256) void bsum_kernel(const float* __restrict__ emb,
                                                   float* __restrict__ Bf) {
    const int k = blockIdx.x * 256 + threadIdx.x;
    Bf[k] = np_sq_sum256(emb + (size_t)k * DD, 1);
}

__global__ __launch_bounds__(256) void asum_kernel(const float* __restrict__ z_e,
                                                   float* __restrict__ Af) {
    const int n = blockIdx.x * 256 + threadIdx.x;
    const int b = n >> 10, t = n & 1023;
    Af[n] = np_sq_sum256(z_e + ((size_t)b << 18) + t, TT);
}

// ---- fused z prep: zt (fp32 [q][d]) + zf (fp16, FRAG-ORDER) + Af ----
__global__ __launch_bounds__(256) void fusedz_kernel(const float* __restrict__ z_e,
                                                     float* __restrict__ zt,
                                                     unsigned short* __restrict__ zf,
                                                     float* __restrict__ Af) {
    __shared__ float tile[64 * 261];
    const int tid = threadIdx.x, l = tid & 63, r = tid >> 6;
    const int n0 = blockIdx.x * 64;           // 512 blocks; n0 multiple of 64
    const int b = n0 >> 10, t0 = n0 & 1023;
    for (int d = r; d < DD; d += 4)
        tile[l * 261 + d] = z_e[(size_t)(b * DD + d) * TT + t0 + l];
    __syncthreads();
    {   // zt write (row-major fp32, coalesced f4)
        const int q = tid >> 2, c0 = (tid & 3) * 64;
        const float* src = &tile[q * 261 + c0];
        float* dzt = zt + (size_t)(n0 + q) * DD + c0;
        #pragma unroll
        for (int i = 0; i < 16; ++i) {
            f4 v;
            v.x = src[4 * i + 0]; v.y = src[4 * i + 1];
            v.z = src[4 * i + 2]; v.w = src[4 * i + 3];
            *(f4*)(dzt + 4 * i) = v;
        }
    }
    {   // zf write in frag-order: 2048 slots of 16B, lane-contiguous stores
        const int g0 = n0 >> 5;               // first of two local groups
        #pragma unroll
        for (int i = 0; i < 8; ++i) {
            const int slot = tid + 256 * i;   // 0..2047
            const int g  = slot >> 10;        // local group 0/1
            const int ks = (slot >> 6) & 15;
            const int ln = slot & 63;
            const int row = g * 32 + (ln & 31);
            const int col = ks * 16 + (ln >> 5) * 8;
            const float* s = &tile[row * 261 + col];
            ushort4 h0, h1;
            h0.x = h16(s[0]); h0.y = h16(s[1]); h0.z = h16(s[2]); h0.w = h16(s[3]);
            h1.x = h16(s[4]); h1.y = h16(s[5]); h1.z = h16(s[6]); h1.w = h16(s[7]);
            unsigned short* dst = zf + (((size_t)(g0 + g) * 16 + ks) * 64 + ln) * 8;
            *(ushort4*)dst       = h0;
            *(ushort4*)(dst + 4) = h1;
        }
    }
    if (tid < 64) Af[n0 + tid] = np_sq_sum256(&tile[tid * 261], 1);
}

// ---- e -> fp16 *1024, FRAG-ORDER ----
__global__ __launch_bounds__(256) void convef_kernel(const float* __restrict__ emb,
                                                     unsigned short* __restrict__ ef) {
    const int slot = blockIdx.x * 256 + threadIdx.x;   // 262144 slots
    const int g = slot >> 10, ks = (slot >> 6) & 15, ln = slot & 63;
    const int k = g * 32 + (ln & 31);
    const int d = ks * 16 + (ln >> 5) * 8;
    const float* s = emb + (size_t)k * DD + d;
    const f4 v0 = *(const f4*)s;
    const f4 v1 = *(const f4*)(s + 4);
    ushort4 h0, h1;
    h0.x = h16(v0.x * 1024.0f); h0.y = h16(v0.y * 1024.0f);
    h0.z = h16(v0.z * 1024.0f); h0.w = h16(v0.w * 1024.0f);
    h1.x = h16(v1.x * 1024.0f); h1.y = h16(v1.y * 1024.0f);
    h1.z = h16(v1.z * 1024.0f); h1.w = h16(v1.w * 1024.0f);
    unsigned short* dst = ef + (size_t)slot * 8;
    *(ushort4*)dst       = h0;
    *(ushort4*)(dst + 4) = h1;
}

// ---- K1: fp16 32x32x16 MFMA scorer, operand-swapped (C: row=code, col=q) ----
// Identical compute/LDS layout to R3; only global addresses changed to the
// frag-order layout -> all staging + prologue loads are contiguous 1KB/wave.
__device__ __forceinline__ void epi32(const f16acc acc, const float* BfLp,
                                      float (*minbuf)[17], int bfbase, int qrow,
                                      int col, float afv, int lane) {
    const f4 b0 = *(const f4*)&BfLp[bfbase];
    const f4 b1 = *(const f4*)&BfLp[bfbase + 8];
    const f4 b2 = *(const f4*)&BfLp[bfbase + 16];
    const f4 b3 = *(const f4*)&BfLp[bfbase + 24];
    float m =    __fmaf_rn(acc[0],  -INV512, b0.x);
    m = fminf(m, __fmaf_rn(acc[1],  -INV512, b0.y));
    m = fminf(m, __fmaf_rn(acc[2],  -INV512, b0.z));
    m = fminf(m, __fmaf_rn(acc[3],  -INV512, b0.w));
    m = fminf(m, __fmaf_rn(acc[4],  -INV512, b1.x));
    m = fminf(m, __fmaf_rn(acc[5],  -INV512, b1.y));
    m = fminf(m, __fmaf_rn(acc[6],  -INV512, b1.z));
    m = fminf(m, __fmaf_rn(acc[7],  -INV512, b1.w));
    m = fminf(m, __fmaf_rn(acc[8],  -INV512, b2.x));
    m = fminf(m, __fmaf_rn(acc[9],  -INV512, b2.y));
    m = fminf(m, __fmaf_rn(acc[10], -INV512, b2.z));
    m = fminf(m, __fmaf_rn(acc[11], -INV512, b2.w));
    m = fminf(m, __fmaf_rn(acc[12], -INV512, b3.x));
    m = fminf(m, __fmaf_rn(acc[13], -INV512, b3.y));
    m = fminf(m, __fmaf_rn(acc[14], -INV512, b3.z));
    m = fminf(m, __fmaf_rn(acc[15], -INV512, b3.w));
    m = fminf(m, __shfl_xor(m, 32));
    if (lane < 32) minbuf[qrow][col] = afv + m;
}

__global__ __launch_bounds__(256, 2) void mfma1_kernel(
    const unsigned short* __restrict__ zf, const unsigned short* __restrict__ ef,
    const float* __restrict__ Af, const float* __restrict__ Bf,
    float* __restrict__ tmp_min) {
    __shared__ unsigned short Bb[32768];   // 64 KiB: [rg4][ks16][lane64][8 f16]
    __shared__ float minbuf[128][17];      // 8.5 KiB, stride 17 conflict-free
    __shared__ float BfL[512];             // 2 KiB

    const int tid  = threadIdx.x;
    const int lane = tid & 63;
    const int w    = tid >> 6;         // 0..3
    const int l31  = lane & 31;
    const int hf   = lane >> 5;        // 0/1
    const int wq   = w & 1;            // q-half (64 rows)
    const int wk   = w >> 1;           // code-half of tile (rg pair)
    const int qt   = blockIdx.x >> 4;  // 256 q-tiles of 128
    const int kb   = blockIdx.x & 15;  // 16 k-slabs of 512 codes

    BfL[tid]       = Bf[kb * 512 + tid];
    BfL[tid + 256] = Bf[kb * 512 + 256 + tid];

    // ---- z resident in registers: B-operand frags (col=q), 128 VGPR ----
    // frag-order: contiguous 1KB per wave-load.
    hfrag zr[2][16];
    #pragma unroll
    for (int cg = 0; cg < 2; ++cg) {
        const unsigned short* zb =
            zf + (((size_t)(qt * 4 + wq * 2 + cg) * 16) * 64 + lane) * 8;
        #pragma unroll
        for (int ks = 0; ks < 16; ++ks)
            zr[cg][ks] = *(const hfrag*)(zb + (size_t)ks * 512);
    }
    const float af0 = Af[qt * 128 + wq * 64 + l31];
    const float af1 = Af[qt * 128 + wq * 64 + 32 + l31];

    // ---- stage e tile 0: wave w stages code-group (kb*16 + kt*4 + w) ----
    const unsigned short* esrc =
        ef + (((size_t)(kb * 16 + w) * 16) * 64 + lane) * 8;
    #pragma unroll
    for (int ks = 0; ks < 16; ++ks)
        GLD16(esrc + ks * 512, Bb + (w * 16 + ks) * 512);
    __syncthreads();

    for (int kt = 0; kt < 4; ++kt) {
        f16acc acc00 = {}, acc01 = {}, acc10 = {}, acc11 = {};
        #pragma unroll
        for (int ks = 0; ks < 16; ++ks) {
            const hfrag e0 = *(const hfrag*)(Bb + ((wk * 2 + 0) * 16 + ks) * 512 + lane * 8);
            const hfrag e1 = *(const hfrag*)(Bb + ((wk * 2 + 1) * 16 + ks) * 512 + lane * 8);
            acc00 = __builtin_amdgcn_mfma_f32_32x32x16_f16(e0, zr[0][ks], acc00, 0, 0, 0);
            acc01 = __builtin_amdgcn_mfma_f32_32x32x16_f16(e0, zr[1][ks], acc01, 0, 0, 0);
            acc10 = __builtin_amdgcn_mfma_f32_32x32x16_f16(e1, zr[0][ks], acc10, 0, 0, 0);
            acc11 = __builtin_amdgcn_mfma_f32_32x32x16_f16(e1, zr[1][ks], acc11, 0, 0, 0);
        }
        __syncthreads();                       // all waves done reading Bb
        if (kt < 3) {                          // stage next tile (shadowed by epilogue)
            const unsigned short* esn = esrc + (size_t)(kt + 1) * 4 * 16 * 512;
            #pragma unroll
            for (int ks = 0; ks < 16; ++ks)
                GLD16(esn + ks * 512, Bb + (w * 16 + ks) * 512);
        }
        {   // epilogue: per-(q, 32-code-group) min into minbuf
            const int bfb0 = kt * 128 + (wk * 2 + 0) * 32 + hf * 4;
            const int bfb1 = kt * 128 + (wk * 2 + 1) * 32 + hf * 4;
            const int qr0 = wq * 64 + l31, qr1 = wq * 64 + 32 + l31;
            const int c0 = kt * 4 + wk * 2, c1 = c0 + 1;
            epi32(acc00, BfL, minbuf, bfb0, qr0, c0, af0, lane);
            epi32(acc01, BfL, minbuf, bfb0, qr1, c0, af1, lane);
            epi32(acc10, BfL, minbuf, bfb1, qr0, c1, af0, lane);
            epi32(acc11, BfL, minbuf, bfb1, qr1, c1, af1, lane);
        }
        if (kt < 3) __syncthreads();           // drains vmcnt -> next tile ready
    }
    __syncthreads();
    // coalesced tmp_min write: 128 rows x 16 groups, full 64B line per row
    {
        const int qloc = tid >> 1, h8 = (tid & 1) * 8;
        const float* mrow = &minbuf[qloc][h8];
        f4 v0, v1;
        v0.x = mrow[0]; v0.y = mrow[1]; v0.z = mrow[2]; v0.w = mrow[3];
        v1.x = mrow[4]; v1.y = mrow[5]; v1.z = mrow[6]; v1.w = mrow[7];
        float* dst = tmp_min + (size_t)(qt * 128 + qloc) * 256 + kb * 16 + h8;
        *(f4*)dst       = v0;
        *(f4*)(dst + 4) = v1;
    }
}

// ---- K2: fused select: per-q min+thr, winner init, bucket scatter ----
__global__ __launch_bounds__(256) void select_kernel(
    const float* __restrict__ tmp_min, int* __restrict__ bcnt,
    int* __restrict__ bucket, int* __restrict__ list, int* __restrict__ cnt,
    unsigned long long* __restrict__ winner) {
    const int tid = threadIdx.x, lane = tid & 63, w = tid >> 6;
    const int q = blockIdx.x * 4 + w;          // 8192 blocks
    const f4 v = *(const f4*)(tmp_min + (size_t)q * 256 + lane * 4);
    float m = fminf(fminf(v.x, v.y), fminf(v.z, v.w));
    #pragma unroll
    for (int off = 1; off < 64; off <<= 1) m = fminf(m, __shfl_xor(m, off));
    const float thr = m + MU;
    if (lane == 0) winner[q] = ~0ULL;
    float vv[4] = {v.x, v.y, v.z, v.w};
    #pragma unroll
    for (int j = 0; j < 4; ++j) {
        if (vv[j] <= thr) {
            const int g = lane * 4 + j;
            const int pos = atomicAdd(&bcnt[g], 1);
            if (pos < BCAP) bucket[g * BCAP + pos] = q;
            else {
                const int op = atomicAdd(cnt, 1);
                if (op < LIST_CAP) list[op] = (q << 8) | g;
            }
        }
    }
}

// ---- K3: bucketed exact re-rank: block per 32-code group, e staged once ----
__global__ __launch_bounds__(256) void rescan_bucket_kernel(
    const float* __restrict__ zt, const float* __restrict__ emb,
    const float* __restrict__ Af, const float* __restrict__ Bf,
    const int* __restrict__ bcnt, const int* __restrict__ bucket,
    unsigned long long* __restrict__ winner) {
    __shared__ float elds[256 * 33];   // [d][k], stride 33 -> conflict-free
    __shared__ float zbuf[8][256];
    __shared__ float bfs[32];
    const int g = blockIdx.x;          // 256 groups
    const int tid = threadIdx.x, lane = tid & 63, w = tid >> 6;
    const int half = lane >> 5, l32 = lane & 31, slot = w * 2 + half;
    {   // stage e rows (coalesced reads, transpose into [d][k])
        const int k = tid >> 3, s0 = (tid & 7) * 32;
        const float* src = emb + (size_t)(g * 32 + k) * DD + s0;
        #pragma unroll
        for (int i = 0; i < 8; ++i) {
            const f4 v = *(const f4*)(src + i * 4);
            elds[(s0 + 4 * i + 0) * 33 + k] = v.x;
            elds[(s0 + 4 * i + 1) * 33 + k] = v.y;
            elds[(s0 + 4 * i + 2) * 33 + k] = v.z;
            elds[(s0 + 4 * i + 3) * 33 + k] = v.w;
        }
        if (tid < 32) bfs[tid] = Bf[g * 32 + tid];
    }
    __syncthreads();
    const int nit = min(bcnt[g], BCAP);
    const int kme = g * 32 + l32;
    for (int base = 0; base < nit; base += 8) {
        const int it = base + slot;
        int q = -1;
        if (it < nit) {
            q = bucket[g * BCAP + it];
            f4* zb = (f4*)&zbuf[slot][0];
            const f4* zsrc = (const f4*)(zt + (size_t)q * DD);
            zb[l32]      = zsrc[l32];
            zb[l32 + 32] = zsrc[l32 + 32];
        }
        __syncthreads();
        if (it < nit) {
            const float* zp = &zbuf[slot][0];
            float c = 0.0f;
            #pragma unroll 8
            for (int d = 0; d < DD; ++d)
                c = __fmaf_rn(zp[d], elds[d * 33 + l32], c);
            float bv = __fsub_rn(__fadd_rn(Af[q], bfs[l32]), __fadd_rn(c, c));
            int bk = kme;
            #pragma unroll
            for (int off = 1; off < 32; off <<= 1) {
                const float ob = __shfl_xor(bv, off);
                const int   ok = __shfl_xor(bk, off);
                if (ob < bv || (ob == bv && ok < bk)) { bv = ob; bk = ok; }
            }
            if (l32 == 0)
                atomicMin(winner + q,
                          (((unsigned long long)__float_as_uint(bv)) << 32) | (unsigned)bk);
        }
        __syncthreads();
    }
}

// ---- K3x: overflow re-rank (per-item, rare) ----
__global__ __launch_bounds__(256) void rescan2_kernel(
    const float* __restrict__ zt, const float* __restrict__ emb,
    const float* __restrict__ Af, const float* __restrict__ Bf,
    const int* __restrict__ list, const int* __restrict__ cnt,
    unsigned long long* __restrict__ winner) {
    __shared__ float zbuf[8][256];
    const int tid = threadIdx.x, lane = tid & 63, w = tid >> 6;
    const int half = lane >> 5, l32 = lane & 31;
    const int slot = blockIdx.x * 8 + w * 2 + half;
    const int slots = gridDim.x * 8;
    const int n = min(*cnt, LIST_CAP);
    f4* zb = (f4*)&zbuf[w * 2 + half][0];
    for (int it = slot; it < n; it += slots) {
        const int id = list[it];
        const int q = id >> 8, g = id & 255;
        const f4* zsrc = (const f4*)(zt + (size_t)q * DD);
        zb[l32]      = zsrc[l32];
        zb[l32 + 32] = zsrc[l32 + 32];
        const int k = g * 32 + l32;
        const f4* e = (const f4*)(emb + (size_t)k * DD);
        float c = 0.0f;
        #pragma unroll 8
        for (int i = 0; i < 64; ++i) {
            const f4 ev = e[i];
            const f4 zv = zb[i];
            c = __fmaf_rn(zv.x, ev.x, c);
            c = __fmaf_rn(zv.y, ev.y, c);
            c = __fmaf_rn(zv.z, ev.z, c);
            c = __fmaf_rn(zv.w, ev.w, c);
        }
        float bv = __fsub_rn(__fadd_rn(Af[q], Bf[k]), __fadd_rn(c, c));
        int bk = k;
        #pragma unroll
        for (int off = 1; off < 32; off <<= 1) {
            const float ob = __shfl_xor(bv, off);
            const int   ok = __shfl_xor(bk, off);
            if (ob < bv || (ob == bv && ok < bk)) { bv = ob; bk = ok; }
        }
        if (l32 == 0)
            atomicMin(winner + q,
                      (((unsigned long long)__float_as_uint(bv)) << 32) | (unsigned)bk);
    }
}

// ---- K4: finalize idx + loss ----
__global__ __launch_bounds__(256) void final_kernel(
    const unsigned long long* __restrict__ winner, float* __restrict__ out_idx,
    int* __restrict__ idx_i, double* __restrict__ loss_acc) {
    __shared__ double ls[4];
    const int tid = threadIdx.x, lane = tid & 63, w = tid >> 6;
    const int q = blockIdx.x * 256 + tid;
    const unsigned long long wv = winner[q];
    const int k = (int)(wv & 0xFFFFFFFFu);
    idx_i[q] = k;
    out_idx[q] = (float)k;
    double s = (double)__uint_as_float((unsigned)(wv >> 32));
    #pragma unroll
    for (int off = 1; off < 64; off <<= 1) s += __shfl_xor(s, off);
    if (lane == 0) ls[w] = s;
    __syncthreads();
    if (tid == 0) atomicAdd(loss_acc, ls[0] + ls[1] + ls[2] + ls[3]);
}

// ================== r5 fallback scorer (ws too small) ==================
__device__ __forceinline__ void ldstage(const float* __restrict__ emb, int st,
                                        int c, int p, f4* g) {
    const int kt = st >> 4, dc = st & 15;
    const float* src = emb + (((size_t)(kt * 512 + p * 128 + c)) << 8) + dc * 16;
    #pragma unroll
    for (int m = 0; m < 4; ++m) g[m] = *(const f4*)(src + 4 * m);
    const float* src2 = src + (64 << 8);
    #pragma unroll
    for (int m = 0; m < 4; ++m) g[4 + m] = *(const f4*)(src2 + 4 * m);
}

__global__ __launch_bounds__(256, 2) void score5_kernel(
    const float* __restrict__ z_e, const float* __restrict__ emb,
    const float* __restrict__ Bf, const float* __restrict__ Af,
    float* __restrict__ out_idx, int* __restrict__ idx_i,
    double* __restrict__ loss_acc) {
    __shared__ float zl[32 * 260];
    __shared__ float etp[64 * 132];
    const int tid = threadIdx.x;
    const int lane = tid & 63;
    const int w = tid >> 6;
    const int n0 = blockIdx.x * 32;
    const int b = n0 >> 10, t0 = n0 & 1023;
    {
        const int q = tid & 31;
        for (int d = tid >> 5; d < DD; d += 8)
            zl[q * 260 + d] = z_e[((size_t)(b * DD + d) << 10) + t0 + q];
    }
    float Aq[8];
    #pragma unroll
    for (int j = 0; j < 8; ++j) Aq[j] = Af[n0 + w * 8 + j];
    float best[8];
    int bidx[8];
    #pragma unroll
    for (int j = 0; j < 8; ++j) { best[j] = 3.0e38f; bidx[j] = 0; }
    f4 g[8];
    ldstage(emb, 0, lane, w, g);
    for (int kt = 0; kt < 16; ++kt) {
        f2 acc[8][4];
        #pragma unroll
        for (int j = 0; j < 8; ++j)
            #pragma unroll
            for (int p2 = 0; p2 < 4; ++p2) acc[j][p2] = (f2){0.0f, 0.0f};
        for (int dc = 0; dc < 16; ++dc) {
            __syncthreads();
            {
                float* dst = etp + lane * 132 + w * 32;
                #pragma unroll
                for (int m = 0; m < 4; ++m) {
                    const f4 a = g[m], bv = g[4 + m];
                    *(f4*)(dst + 8 * m)     = __builtin_shufflevector(a, bv, 0, 4, 1, 5);
                    *(f4*)(dst + 8 * m + 4) = __builtin_shufflevector(a, bv, 2, 6, 3, 7);
                }
            }
            __syncthreads();
            const int st = kt * 16 + dc;
            ldstage(emb, st < 255 ? st + 1 : 255, lane, w, g);
            #pragma unroll
            for (int s4 = 0; s4 < 4; ++s4) {
                const int dd0 = s4 * 4;
                f4 zv[8];
                #pragma unroll
                for (int j = 0; j < 8; ++j)
                    zv[j] = *(const f4*)(zl + (w * 8 + j) * 260 + dc * 16 + dd0);
                f4 ev[4][2];
                #pragma unroll
                for (int p2 = 0; p2 < 4; ++p2) {
                    const float* eb = etp + lane * 132 + p2 * 32 + dd0 * 2;
                    ev[p2][0] = *(const f4*)(eb);
                    ev[p2][1] = *(const f4*)(eb + 4);
                }
                #pragma unroll
                for (int j = 0; j < 8; ++j) {
                    #pragma unroll
                    for (int dd = 0; dd < 4; ++dd) {
                        const float zs = zv[j][dd];
                        const f2 z2 = {zs, zs};
                        #pragma unroll
                        for (int p2 = 0; p2 < 4; ++p2) {
                            const f4 evv = ev[p2][dd >> 1];
                            const f2 e2 = (dd & 1)
                                ? __builtin_shufflevector(evv, evv, 2, 3)
                                : __builtin_shufflevector(evv, evv, 0, 1);
                            acc[j][p2] = PKFMA(z2, e2, acc[j][p2]);
                        }
                    }
                }
            }
        }
        const int kt0 = kt * 512;
        float Bk[8];
        #pragma unroll
        for (int i = 0; i < 8; ++i) Bk[i] = Bf[kt0 + 64 * i + lane];
        #pragma unroll
        for (int p2 = 0; p2 < 4; ++p2) {
            #pragma unroll
            for (int s = 0; s < 2; ++s) {
                const int i = 2 * p2 + s;
                #pragma unroll
                for (int j = 0; j < 8; ++j) {
                    const float C = s ? acc[j][p2].y : acc[j][p2].x;
                    const float dist = __fsub_rn(__fadd_rn(Aq[j], Bk[i]), __fadd_rn(C, C));
                    const int k = kt0 + 64 * i + lane;
                    if (dist < best[j]) { best[j] = dist; bidx[j] = k; }
                }
            }
        }
    }
    #pragma unroll
    for (int j = 0; j < 8; ++j) {
        float bb = best[j];
        int bi = bidx[j];
        #pragma unroll
        for (int off = 1; off < 64; off <<= 1) {
            const float ob = __shfl_xor(bb, off);
            const int oi = __shfl_xor(bi, off);
            if (ob < bb || (ob == bb && oi < bi)) { bb = ob; bi = oi; }
        }
        best[j] = bb; bidx[j] = bi;
    }
    if (lane == 0) {
        double lp = 0.0;
        #pragma unroll
        for (int j = 0; j < 8; ++j) {
            const int n = n0 + w * 8 + j;
            out_idx[n] = (float)bidx[j];
            idx_i[n] = bidx[j];
            lp += (double)best[j];
        }
        atomicAdd(loss_acc, lp);
    }
}

// ================== shared epilogue kernels ==================
__global__ __launch_bounds__(256) void gather_kernel(const float* __restrict__ emb,
                                                     const int* __restrict__ idx_i,
                                                     float* __restrict__ zq) {
    const int blk = blockIdx.x;
    const int b = blk >> 4;
    const int t0 = (blk & 15) * 64;
    const int q = threadIdx.x & 63;
    const int dc = threadIdx.x >> 6;
    const int n = b * TT + t0 + q;
    const int k = idx_i[n];
    const f4* erow = (const f4*)(emb + (size_t)k * DD + dc * 64);
    #pragma unroll
    for (int jj = 0; jj < 16; ++jj) {
        const f4 v = erow[jj];
        const int d = dc * 64 + jj * 4;
        zq[(size_t)(b * DD + d + 0) * TT + t0 + q] = v.x;
        zq[(size_t)(b * DD + d + 1) * TT + t0 + q] = v.y;
        zq[(size_t)(b * DD + d + 2) * TT + t0 + q] = v.z;
        zq[(size_t)(b * DD + d + 3) * TT + t0 + q] = v.w;
    }
}

__global__ void fin_kernel(const double* __restrict__ loss_acc,
                           float* __restrict__ out_loss) {
    out_loss[0] = (float)(loss_acc[0] * (1.0 / ((double)BB * DD * TT)));
}

extern "C" void kernel_launch(void* const* d_in, const int* in_sizes, int n_in,
                              void* d_out, int out_size, void* d_ws, size_t ws_size,
                              hipStream_t stream) {
    const float* z_e = (const float*)d_in[0];
    const float* emb = (const float*)d_in[1];

    float* out      = (float*)d_out;
    float* zq       = out;
    float* out_loss = out + (size_t)BB * DD * TT;
    float* out_idx  = out_loss + 1;

    char* ws = (char*)d_ws;
    double* loss_acc = (double*)(ws + WS_LOSS);
    float*  Bf       = (float*)(ws + WS_BF);
    float*  Af       = (float*)(ws + WS_AF);
    int*    idx_i    = (int*)(ws + WS_IDX);

    hipMemsetAsync(d_ws, 0, 1088, stream);
    bsum_kernel<<<KK / 256, 256, 0, stream>>>(emb, Bf);

    if (ws_size >= (size_t)WS_NEED) {
        int*    cnt    = (int*)(ws + WS_CNT);
        int*    bcnt   = (int*)(ws + WS_BCNT);
        unsigned long long* winner = (unsigned long long*)(ws + WS_WIN);
        float*  zt     = (float*)(ws + WS_ZT);
        float*  tmp_min = (float*)(ws + WS_TMIN);
        int*    bucket = (int*)(ws + WS_BKT);
        int*    list   = (int*)(ws + WS_LIST);
        unsigned short* zf = (unsigned short*)(ws + WS_ZF);
        unsigned short* ef = (unsigned short*)(ws + WS_EF);

        fusedz_kernel<<<(BB * TT) / 64, 256, 0, stream>>>(z_e, zt, zf, Af);
        convef_kernel<<<(KK * DD / 8) / 256, 256, 0, stream>>>(emb, ef);
        mfma1_kernel<<<(BB * TT / 128) * 16, 256, 0, stream>>>(zf, ef, Af, Bf, tmp_min);
        select_kernel<<<(BB * TT) / 4, 256, 0, stream>>>(tmp_min, bcnt, bucket, list, cnt, winner);
        rescan_bucket_kernel<<<256, 256, 0, stream>>>(zt, emb, Af, Bf, bcnt, bucket, winner);
        rescan2_kernel<<<128, 256, 0, stream>>>(zt, emb, Af, Bf, list, cnt, winner);
        final_kernel<<<(BB * TT) / 256, 256, 0, stream>>>(winner, out_idx, idx_i, loss_acc);
    } else {
        asum_kernel<<<(BB * TT) / 256, 256, 0, stream>>>(z_e, Af);
        score5_kernel<<<(BB * TT) / 32, 256, 0, stream>>>(z_e, emb, Bf, Af, out_idx, idx_i, loss_acc);
    }

    gather_kernel<<<(BB * TT) / 64, 256, 0, stream>>>(emb, idx_i, zq);
    fin_kernel<<<1, 1, 0, stream>>>(loss_acc, out_loss);
}

// Round 5
// 400.884 us; speedup vs baseline: 1.8344x; 1.1666x over previous
//
#include <hip/hip_runtime.h>
#include <stdint.h>

#define BB 32
#define DD 256
#define TT 1024
#define KK 8192

typedef __attribute__((ext_vector_type(2))) float f2;
typedef __attribute__((ext_vector_type(4))) float f4;
typedef __attribute__((ext_vector_type(8))) _Float16 hfrag;   // 8 f16 = 4 VGPR
typedef __attribute__((ext_vector_type(16))) float f16acc;    // 32x32 MFMA acc

#if __has_builtin(__builtin_elementwise_fma)
#define PKFMA(a, b, c) __builtin_elementwise_fma(a, b, c)
#else
static __device__ __forceinline__ f2 pkfma_(f2 a, f2 b, f2 c) {
    f2 r; r.x = __fmaf_rn(a.x, b.x, c.x); r.y = __fmaf_rn(a.y, b.y, c.y); return r;
}
#define PKFMA(a, b, c) pkfma_(a, b, c)
#endif

#define GLD16(gp, lp)                                                          \
    __builtin_amdgcn_global_load_lds(                                          \
        (const __attribute__((address_space(1))) uint32_t*)(gp),               \
        (__attribute__((address_space(3))) uint32_t*)(lp), 16, 0, 0)

#define MU 3.0e-4f
#define BCAP 4096
#define LIST_CAP 1048576
// e is pre-scaled by 1024 before fp16 cast; dist = Af+Bf - 2*dot/1024
#define INV512 0.001953125f

// fragment-order layout for fp16 operands (both zf and ef):
//   slot(g, ks, lane) at short-offset ((g*16 + ks)*64 + lane)*8
//   holds row g*32 + (lane&31), cols ks*16 + (lane>>5)*8 .. +8
// -> every wave-level 16B/lane access (GLD16 staging, zr prologue) is one
//    contiguous 1KB burst (m173 pre-swizzled-source pattern).

// ---------------- fast-path ws layout (bytes) ----------------
#define WS_LOSS   0            // double
#define WS_CNT    8            // int (overflow count)
#define WS_BCNT   16           // int[256]
#define WS_BF     1088
#define WS_AF     33856
#define WS_IDX    164928
#define WS_WIN    296000
#define WS_ZT     558144
#define WS_TMIN   34112576
#define WS_BKT    67667008
#define WS_LIST   71861312
#define WS_ZF     76055616     // fp16 z  frag-order, 16.8 MB
#define WS_EF     92832832     // fp16 e*1024 frag-order, 4.2 MB
#define WS_NEED   97027136

__device__ __forceinline__ unsigned short h16(float x) {
    _Float16 t = (_Float16)x;                    // RNE
    return __builtin_bit_cast(unsigned short, t);
}

// Bit-exact numpy pairwise_sum of x[i]^2, n=256.
__device__ __forceinline__ float np_sq_sum256(const float* __restrict__ base, int stride) {
    float res[2];
    #pragma unroll
    for (int blk = 0; blk < 2; ++blk) {
        const int o = blk * 128;
        float r[8];
        #pragma unroll
        for (int j = 0; j < 8; ++j) {
            const float x = base[(o + j) * stride];
            r[j] = __fmul_rn(x, x);
        }
        for (int i = 8; i < 128; i += 8) {
            #pragma unroll
            for (int j = 0; j < 8; ++j) {
                const float x = base[(o + i + j) * stride];
                r[j] = __fadd_rn(r[j], __fmul_rn(x, x));
            }
        }
        res[blk] = __fadd_rn(__fadd_rn(__fadd_rn(r[0], r[1]), __fadd_rn(r[2], r[3])),
                             __fadd_rn(__fadd_rn(r[4], r[5]), __fadd_rn(r[6], r[7])));
    }
    return __fadd_rn(res[0], res[1]);
}

__global__ __launch_bounds__(256) void bsum_kernel(const float* __restrict__ emb,
                                                   float* __restrict__ Bf) {
    const int k = blockIdx.x * 256 + threadIdx.x;
    Bf[k] = np_sq_sum256(emb + (size_t)k * DD, 1);
}

__global__ __launch_bounds__(256) void asum_kernel(const float* __restrict__ z_e,
                                                   float* __restrict__ Af) {
    const int n = blockIdx.x * 256 + threadIdx.x;
    const int b = n >> 10, t = n & 1023;
    Af[n] = np_sq_sum256(z_e + ((size_t)b << 18) + t, TT);
}

// ---- fused z prep: zt (fp32 [q][d]) + zf (fp16, FRAG-ORDER) + Af ----
__global__ __launch_bounds__(256) void fusedz_kernel(const float* __restrict__ z_e,
                                                     float* __restrict__ zt,
                                                     unsigned short* __restrict__ zf,
                                                     float* __restrict__ Af) {
    __shared__ float tile[64 * 261];
    const int tid = threadIdx.x, l = tid & 63, r = tid >> 6;
    const int n0 = blockIdx.x * 64;           // 512 blocks; n0 multiple of 64
    const int b = n0 >> 10, t0 = n0 & 1023;
    for (int d = r; d < DD; d += 4)
        tile[l * 261 + d] = z_e[(size_t)(b * DD + d) * TT + t0 + l];
    __syncthreads();
    {   // zt write (row-major fp32, coalesced f4)
        const int q = tid >> 2, c0 = (tid & 3) * 64;
        const float* src = &tile[q * 261 + c0];
        float* dzt = zt + (size_t)(n0 + q) * DD + c0;
        #pragma unroll
        for (int i = 0; i < 16; ++i) {
            f4 v;
            v.x = src[4 * i + 0]; v.y = src[4 * i + 1];
            v.z = src[4 * i + 2]; v.w = src[4 * i + 3];
            *(f4*)(dzt + 4 * i) = v;
        }
    }
    {   // zf write in frag-order: 2048 slots of 16B, lane-contiguous stores
        const int g0 = n0 >> 5;               // first of two local groups
        #pragma unroll
        for (int i = 0; i < 8; ++i) {
            const int slot = tid + 256 * i;   // 0..2047
            const int g  = slot >> 10;        // local group 0/1
            const int ks = (slot >> 6) & 15;
            const int ln = slot & 63;
            const int row = g * 32 + (ln & 31);
            const int col = ks * 16 + (ln >> 5) * 8;
            const float* s = &tile[row * 261 + col];
            ushort4 h0, h1;
            h0.x = h16(s[0]); h0.y = h16(s[1]); h0.z = h16(s[2]); h0.w = h16(s[3]);
            h1.x = h16(s[4]); h1.y = h16(s[5]); h1.z = h16(s[6]); h1.w = h16(s[7]);
            unsigned short* dst = zf + (((size_t)(g0 + g) * 16 + ks) * 64 + ln) * 8;
            *(ushort4*)dst       = h0;
            *(ushort4*)(dst + 4) = h1;
        }
    }
    if (tid < 64) Af[n0 + tid] = np_sq_sum256(&tile[tid * 261], 1);
}

// ---- e -> fp16 *1024, FRAG-ORDER ----
__global__ __launch_bounds__(256) void convef_kernel(const float* __restrict__ emb,
                                                     unsigned short* __restrict__ ef) {
    const int slot = blockIdx.x * 256 + threadIdx.x;   // 262144 slots
    const int g = slot >> 10, ks = (slot >> 6) & 15, ln = slot & 63;
    const int k = g * 32 + (ln & 31);
    const int d = ks * 16 + (ln >> 5) * 8;
    const float* s = emb + (size_t)k * DD + d;
    const f4 v0 = *(const f4*)s;
    const f4 v1 = *(const f4*)(s + 4);
    ushort4 h0, h1;
    h0.x = h16(v0.x * 1024.0f); h0.y = h16(v0.y * 1024.0f);
    h0.z = h16(v0.z * 1024.0f); h0.w = h16(v0.w * 1024.0f);
    h1.x = h16(v1.x * 1024.0f); h1.y = h16(v1.y * 1024.0f);
    h1.z = h16(v1.z * 1024.0f); h1.w = h16(v1.w * 1024.0f);
    unsigned short* dst = ef + (size_t)slot * 8;
    *(ushort4*)dst       = h0;
    *(ushort4*)(dst + 4) = h1;
}

// ---- K1: fp16 32x32x16 MFMA scorer, operand-swapped (C: row=code, col=q) ----
__device__ __forceinline__ void epi32(const f16acc acc, const float* BfLp,
                                      float (*minbuf)[17], int bfbase, int qrow,
                                      int col, float afv, int lane) {
    const f4 b0 = *(const f4*)&BfLp[bfbase];
    const f4 b1 = *(const f4*)&BfLp[bfbase + 8];
    const f4 b2 = *(const f4*)&BfLp[bfbase + 16];
    const f4 b3 = *(const f4*)&BfLp[bfbase + 24];
    float m =    __fmaf_rn(acc[0],  -INV512, b0.x);
    m = fminf(m, __fmaf_rn(acc[1],  -INV512, b0.y));
    m = fminf(m, __fmaf_rn(acc[2],  -INV512, b0.z));
    m = fminf(m, __fmaf_rn(acc[3],  -INV512, b0.w));
    m = fminf(m, __fmaf_rn(acc[4],  -INV512, b1.x));
    m = fminf(m, __fmaf_rn(acc[5],  -INV512, b1.y));
    m = fminf(m, __fmaf_rn(acc[6],  -INV512, b1.z));
    m = fminf(m, __fmaf_rn(acc[7],  -INV512, b1.w));
    m = fminf(m, __fmaf_rn(acc[8],  -INV512, b2.x));
    m = fminf(m, __fmaf_rn(acc[9],  -INV512, b2.y));
    m = fminf(m, __fmaf_rn(acc[10], -INV512, b2.z));
    m = fminf(m, __fmaf_rn(acc[11], -INV512, b2.w));
    m = fminf(m, __fmaf_rn(acc[12], -INV512, b3.x));
    m = fminf(m, __fmaf_rn(acc[13], -INV512, b3.y));
    m = fminf(m, __fmaf_rn(acc[14], -INV512, b3.z));
    m = fminf(m, __fmaf_rn(acc[15], -INV512, b3.w));
    m = fminf(m, __shfl_xor(m, 32));
    if (lane < 32) minbuf[qrow][col] = afv + m;
}

__global__ __launch_bounds__(256, 2) void mfma1_kernel(
    const unsigned short* __restrict__ zf, const unsigned short* __restrict__ ef,
    const float* __restrict__ Af, const float* __restrict__ Bf,
    float* __restrict__ tmp_min) {
    __shared__ unsigned short Bb[32768];   // 64 KiB: [rg4][ks16][lane64][8 f16]
    __shared__ float minbuf[128][17];      // 8.5 KiB, stride 17 conflict-free
    __shared__ float BfL[512];             // 2 KiB

    const int tid  = threadIdx.x;
    const int lane = tid & 63;
    const int w    = tid >> 6;         // 0..3
    const int l31  = lane & 31;
    const int hf   = lane >> 5;        // 0/1
    const int wq   = w & 1;            // q-half (64 rows)
    const int wk   = w >> 1;           // code-half of tile (rg pair)
    const int qt   = blockIdx.x >> 4;  // 256 q-tiles of 128
    const int kb   = blockIdx.x & 15;  // 16 k-slabs of 512 codes

    BfL[tid]       = Bf[kb * 512 + tid];
    BfL[tid + 256] = Bf[kb * 512 + 256 + tid];

    // ---- z resident in registers: B-operand frags (col=q), 128 VGPR ----
    hfrag zr[2][16];
    #pragma unroll
    for (int cg = 0; cg < 2; ++cg) {
        const unsigned short* zb =
            zf + (((size_t)(qt * 4 + wq * 2 + cg) * 16) * 64 + lane) * 8;
        #pragma unroll
        for (int ks = 0; ks < 16; ++ks)
            zr[cg][ks] = *(const hfrag*)(zb + (size_t)ks * 512);
    }
    const float af0 = Af[qt * 128 + wq * 64 + l31];
    const float af1 = Af[qt * 128 + wq * 64 + 32 + l31];

    // ---- stage e tile 0: wave w stages code-group (kb*16 + kt*4 + w) ----
    const unsigned short* esrc =
        ef + (((size_t)(kb * 16 + w) * 16) * 64 + lane) * 8;
    #pragma unroll
    for (int ks = 0; ks < 16; ++ks)
        GLD16(esrc + ks * 512, Bb + (w * 16 + ks) * 512);
    __syncthreads();

    for (int kt = 0; kt < 4; ++kt) {
        f16acc acc00 = {}, acc01 = {}, acc10 = {}, acc11 = {};
        #pragma unroll
        for (int ks = 0; ks < 16; ++ks) {
            const hfrag e0 = *(const hfrag*)(Bb + ((wk * 2 + 0) * 16 + ks) * 512 + lane * 8);
            const hfrag e1 = *(const hfrag*)(Bb + ((wk * 2 + 1) * 16 + ks) * 512 + lane * 8);
            acc00 = __builtin_amdgcn_mfma_f32_32x32x16_f16(e0, zr[0][ks], acc00, 0, 0, 0);
            acc01 = __builtin_amdgcn_mfma_f32_32x32x16_f16(e0, zr[1][ks], acc01, 0, 0, 0);
            acc10 = __builtin_amdgcn_mfma_f32_32x32x16_f16(e1, zr[0][ks], acc10, 0, 0, 0);
            acc11 = __builtin_amdgcn_mfma_f32_32x32x16_f16(e1, zr[1][ks], acc11, 0, 0, 0);
        }
        __syncthreads();                       // all waves done reading Bb
        if (kt < 3) {                          // stage next tile (shadowed by epilogue)
            const unsigned short* esn = esrc + (size_t)(kt + 1) * 4 * 16 * 512;
            #pragma unroll
            for (int ks = 0; ks < 16; ++ks)
                GLD16(esn + ks * 512, Bb + (w * 16 + ks) * 512);
        }
        {   // epilogue: per-(q, 32-code-group) min into minbuf
            const int bfb0 = kt * 128 + (wk * 2 + 0) * 32 + hf * 4;
            const int bfb1 = kt * 128 + (wk * 2 + 1) * 32 + hf * 4;
            const int qr0 = wq * 64 + l31, qr1 = wq * 64 + 32 + l31;
            const int c0 = kt * 4 + wk * 2, c1 = c0 + 1;
            epi32(acc00, BfL, minbuf, bfb0, qr0, c0, af0, lane);
            epi32(acc01, BfL, minbuf, bfb0, qr1, c0, af1, lane);
            epi32(acc10, BfL, minbuf, bfb1, qr0, c1, af0, lane);
            epi32(acc11, BfL, minbuf, bfb1, qr1, c1, af1, lane);
        }
        if (kt < 3) __syncthreads();           // drains vmcnt -> next tile ready
    }
    __syncthreads();
    // coalesced tmp_min write: 128 rows x 16 groups, full 64B line per row
    {
        const int qloc = tid >> 1, h8 = (tid & 1) * 8;
        const float* mrow = &minbuf[qloc][h8];
        f4 v0, v1;
        v0.x = mrow[0]; v0.y = mrow[1]; v0.z = mrow[2]; v0.w = mrow[3];
        v1.x = mrow[4]; v1.y = mrow[5]; v1.z = mrow[6]; v1.w = mrow[7];
        float* dst = tmp_min + (size_t)(qt * 128 + qloc) * 256 + kb * 16 + h8;
        *(f4*)dst       = v0;
        *(f4*)(dst + 4) = v1;
    }
}

// ---- K2: fused select: per-q min+thr, winner init, bucket scatter ----
__global__ __launch_bounds__(256) void select_kernel(
    const float* __restrict__ tmp_min, int* __restrict__ bcnt,
    int* __restrict__ bucket, int* __restrict__ list, int* __restrict__ cnt,
    unsigned long long* __restrict__ winner) {
    const int tid = threadIdx.x, lane = tid & 63, w = tid >> 6;
    const int q = blockIdx.x * 4 + w;          // 8192 blocks
    const f4 v = *(const f4*)(tmp_min + (size_t)q * 256 + lane * 4);
    float m = fminf(fminf(v.x, v.y), fminf(v.z, v.w));
    #pragma unroll
    for (int off = 1; off < 64; off <<= 1) m = fminf(m, __shfl_xor(m, off));
    const float thr = m + MU;
    if (lane == 0) winner[q] = ~0ULL;
    float vv[4] = {v.x, v.y, v.z, v.w};
    #pragma unroll
    for (int j = 0; j < 4; ++j) {
        if (vv[j] <= thr) {
            const int g = lane * 4 + j;
            const int pos = atomicAdd(&bcnt[g], 1);
            if (pos < BCAP) bucket[g * BCAP + pos] = q;
            else {
                const int op = atomicAdd(cnt, 1);
                if (op < LIST_CAP) list[op] = (q << 8) | g;
            }
        }
    }
}

// ---- K3: bucketed exact re-rank, 8 slice-blocks per 32-code group ----
// grid 2048 = 256 groups x 8 slices; each block stages the group's e tile
// (L3-resident, cheap) and processes items it = slice*8+slot, stride 64.
// No per-item barriers: zbuf[slot] is written and read by the same 32 lanes
// (wave-local LDS ordering via lgkmcnt). Per-item arithmetic is byte-identical
// to the verified serial-fmaf form -> bv bit patterns unchanged.
__global__ __launch_bounds__(256) void rescan_bucket_kernel(
    const float* __restrict__ zt, const float* __restrict__ emb,
    const float* __restrict__ Af, const float* __restrict__ Bf,
    const int* __restrict__ bcnt, const int* __restrict__ bucket,
    unsigned long long* __restrict__ winner) {
    __shared__ float elds[256 * 33];   // [d][k], stride 33 -> conflict-free
    __shared__ float zbuf[8][256];
    __shared__ float bfs[32];
    const int g     = blockIdx.x >> 3;     // 256 groups
    const int slice = blockIdx.x & 7;      // 8 slices per group
    const int tid = threadIdx.x, lane = tid & 63, w = tid >> 6;
    const int half = lane >> 5, l32 = lane & 31, slot = w * 2 + half;
    {   // stage e rows (coalesced reads, transpose into [d][k])
        const int k = tid >> 3, s0 = (tid & 7) * 32;
        const float* src = emb + (size_t)(g * 32 + k) * DD + s0;
        #pragma unroll
        for (int i = 0; i < 8; ++i) {
            const f4 v = *(const f4*)(src + i * 4);
            elds[(s0 + 4 * i + 0) * 33 + k] = v.x;
            elds[(s0 + 4 * i + 1) * 33 + k] = v.y;
            elds[(s0 + 4 * i + 2) * 33 + k] = v.z;
            elds[(s0 + 4 * i + 3) * 33 + k] = v.w;
        }
        if (tid < 32) bfs[tid] = Bf[g * 32 + tid];
    }
    __syncthreads();
    const int nit = min(bcnt[g], BCAP);
    const int kme = g * 32 + l32;
    for (int it = slice * 8 + slot; it < nit; it += 64) {
        const int q = bucket[g * BCAP + it];
        {
            f4* zb = (f4*)&zbuf[slot][0];
            const f4* zsrc = (const f4*)(zt + (size_t)q * DD);
            zb[l32]      = zsrc[l32];
            zb[l32 + 32] = zsrc[l32 + 32];
        }
        const float* zp = &zbuf[slot][0];
        float c = 0.0f;
        #pragma unroll 8
        for (int d = 0; d < DD; ++d)
            c = __fmaf_rn(zp[d], elds[d * 33 + l32], c);
        float bv = __fsub_rn(__fadd_rn(Af[q], bfs[l32]), __fadd_rn(c, c));
        int bk = kme;
        #pragma unroll
        for (int off = 1; off < 32; off <<= 1) {
            const float ob = __shfl_xor(bv, off);
            const int   ok = __shfl_xor(bk, off);
            if (ob < bv || (ob == bv && ok < bk)) { bv = ob; bk = ok; }
        }
        if (l32 == 0)
            atomicMin(winner + q,
                      (((unsigned long long)__float_as_uint(bv)) << 32) | (unsigned)bk);
    }
}

// ---- K3x: overflow re-rank (per-item, rare) ----
__global__ __launch_bounds__(256) void rescan2_kernel(
    const float* __restrict__ zt, const float* __restrict__ emb,
    const float* __restrict__ Af, const float* __restrict__ Bf,
    const int* __restrict__ list, const int* __restrict__ cnt,
    unsigned long long* __restrict__ winner) {
    __shared__ float zbuf[8][256];
    const int tid = threadIdx.x, lane = tid & 63, w = tid >> 6;
    const int half = lane >> 5, l32 = lane & 31;
    const int slot = blockIdx.x * 8 + w * 2 + half;
    const int slots = gridDim.x * 8;
    const int n = min(*cnt, LIST_CAP);
    f4* zb = (f4*)&zbuf[w * 2 + half][0];
    for (int it = slot; it < n; it += slots) {
        const int id = list[it];
        const int q = id >> 8, g = id & 255;
        const f4* zsrc = (const f4*)(zt + (size_t)q * DD);
        zb[l32]      = zsrc[l32];
        zb[l32 + 32] = zsrc[l32 + 32];
        const int k = g * 32 + l32;
        const f4* e = (const f4*)(emb + (size_t)k * DD);
        float c = 0.0f;
        #pragma unroll 8
        for (int i = 0; i < 64; ++i) {
            const f4 ev = e[i];
            const f4 zv = zb[i];
            c = __fmaf_rn(zv.x, ev.x, c);
            c = __fmaf_rn(zv.y, ev.y, c);
            c = __fmaf_rn(zv.z, ev.z, c);
            c = __fmaf_rn(zv.w, ev.w, c);
        }
        float bv = __fsub_rn(__fadd_rn(Af[q], Bf[k]), __fadd_rn(c, c));
        int bk = k;
        #pragma unroll
        for (int off = 1; off < 32; off <<= 1) {
            const float ob = __shfl_xor(bv, off);
            const int   ok = __shfl_xor(bk, off);
            if (ob < bv || (ob == bv && ok < bk)) { bv = ob; bk = ok; }
        }
        if (l32 == 0)
            atomicMin(winner + q,
                      (((unsigned long long)__float_as_uint(bv)) << 32) | (unsigned)bk);
    }
}

// ---- K4: finalize idx + loss ----
__global__ __launch_bounds__(256) void final_kernel(
    const unsigned long long* __restrict__ winner, float* __restrict__ out_idx,
    int* __restrict__ idx_i, double* __restrict__ loss_acc) {
    __shared__ double ls[4];
    const int tid = threadIdx.x, lane = tid & 63, w = tid >> 6;
    const int q = blockIdx.x * 256 + tid;
    const unsigned long long wv = winner[q];
    const int k = (int)(wv & 0xFFFFFFFFu);
    idx_i[q] = k;
    out_idx[q] = (float)k;
    double s = (double)__uint_as_float((unsigned)(wv >> 32));
    #pragma unroll
    for (int off = 1; off < 64; off <<= 1) s += __shfl_xor(s, off);
    if (lane == 0) ls[w] = s;
    __syncthreads();
    if (tid == 0) atomicAdd(loss_acc, ls[0] + ls[1] + ls[2] + ls[3]);
}

// ================== r5 fallback scorer (ws too small) ==================
__device__ __forceinline__ void ldstage(const float* __restrict__ emb, int st,
                                        int c, int p, f4* g) {
    const int kt = st >> 4, dc = st & 15;
    const float* src = emb + (((size_t)(kt * 512 + p * 128 + c)) << 8) + dc * 16;
    #pragma unroll
    for (int m = 0; m < 4; ++m) g[m] = *(const f4*)(src + 4 * m);
    const float* src2 = src + (64 << 8);
    #pragma unroll
    for (int m = 0; m < 4; ++m) g[4 + m] = *(const f4*)(src2 + 4 * m);
}

__global__ __launch_bounds__(256, 2) void score5_kernel(
    const float* __restrict__ z_e, const float* __restrict__ emb,
    const float* __restrict__ Bf, const float* __restrict__ Af,
    float* __restrict__ out_idx, int* __restrict__ idx_i,
    double* __restrict__ loss_acc) {
    __shared__ float zl[32 * 260];
    __shared__ float etp[64 * 132];
    const int tid = threadIdx.x;
    const int lane = tid & 63;
    const int w = tid >> 6;
    const int n0 = blockIdx.x * 32;
    const int b = n0 >> 10, t0 = n0 & 1023;
    {
        const int q = tid & 31;
        for (int d = tid >> 5; d < DD; d += 8)
            zl[q * 260 + d] = z_e[((size_t)(b * DD + d) << 10) + t0 + q];
    }
    float Aq[8];
    #pragma unroll
    for (int j = 0; j < 8; ++j) Aq[j] = Af[n0 + w * 8 + j];
    float best[8];
    int bidx[8];
    #pragma unroll
    for (int j = 0; j < 8; ++j) { best[j] = 3.0e38f; bidx[j] = 0; }
    f4 g[8];
    ldstage(emb, 0, lane, w, g);
    for (int kt = 0; kt < 16; ++kt) {
        f2 acc[8][4];
        #pragma unroll
        for (int j = 0; j < 8; ++j)
            #pragma unroll
            for (int p2 = 0; p2 < 4; ++p2) acc[j][p2] = (f2){0.0f, 0.0f};
        for (int dc = 0; dc < 16; ++dc) {
            __syncthreads();
            {
                float* dst = etp + lane * 132 + w * 32;
                #pragma unroll
                for (int m = 0; m < 4; ++m) {
                    const f4 a = g[m], bv = g[4 + m];
                    *(f4*)(dst + 8 * m)     = __builtin_shufflevector(a, bv, 0, 4, 1, 5);
                    *(f4*)(dst + 8 * m + 4) = __builtin_shufflevector(a, bv, 2, 6, 3, 7);
                }
            }
            __syncthreads();
            const int st = kt * 16 + dc;
            ldstage(emb, st < 255 ? st + 1 : 255, lane, w, g);
            #pragma unroll
            for (int s4 = 0; s4 < 4; ++s4) {
                const int dd0 = s4 * 4;
                f4 zv[8];
                #pragma unroll
                for (int j = 0; j < 8; ++j)
                    zv[j] = *(const f4*)(zl + (w * 8 + j) * 260 + dc * 16 + dd0);
                f4 ev[4][2];
                #pragma unroll
                for (int p2 = 0; p2 < 4; ++p2) {
                    const float* eb = etp + lane * 132 + p2 * 32 + dd0 * 2;
                    ev[p2][0] = *(const f4*)(eb);
                    ev[p2][1] = *(const f4*)(eb + 4);
                }
                #pragma unroll
                for (int j = 0; j < 8; ++j) {
                    #pragma unroll
                    for (int dd = 0; dd < 4; ++dd) {
                        const float zs = zv[j][dd];
                        const f2 z2 = {zs, zs};
                        #pragma unroll
                        for (int p2 = 0; p2 < 4; ++p2) {
                            const f4 evv = ev[p2][dd >> 1];
                            const f2 e2 = (dd & 1)
                                ? __builtin_shufflevector(evv, evv, 2, 3)
                                : __builtin_shufflevector(evv, evv, 0, 1);
                            acc[j][p2] = PKFMA(z2, e2, acc[j][p2]);
                        }
                    }
                }
            }
        }
        const int kt0 = kt * 512;
        float Bk[8];
        #pragma unroll
        for (int i = 0; i < 8; ++i) Bk[i] = Bf[kt0 + 64 * i + lane];
        #pragma unroll
        for (int p2 = 0; p2 < 4; ++p2) {
            #pragma unroll
            for (int s = 0; s < 2; ++s) {
                const int i = 2 * p2 + s;
                #pragma unroll
                for (int j = 0; j < 8; ++j) {
                    const float C = s ? acc[j][p2].y : acc[j][p2].x;
                    const float dist = __fsub_rn(__fadd_rn(Aq[j], Bk[i]), __fadd_rn(C, C));
                    const int k = kt0 + 64 * i + lane;
                    if (dist < best[j]) { best[j] = dist; bidx[j] = k; }
                }
            }
        }
    }
    #pragma unroll
    for (int j = 0; j < 8; ++j) {
        float bb = best[j];
        int bi = bidx[j];
        #pragma unroll
        for (int off = 1; off < 64; off <<= 1) {
            const float ob = __shfl_xor(bb, off);
            const int oi = __shfl_xor(bi, off);
            if (ob < bb || (ob == bb && oi < bi)) { bb = ob; bi = oi; }
        }
        best[j] = bb; bidx[j] = bi;
    }
    if (lane == 0) {
        double lp = 0.0;
        #pragma unroll
        for (int j = 0; j < 8; ++j) {
            const int n = n0 + w * 8 + j;
            out_idx[n] = (float)bidx[j];
            idx_i[n] = bidx[j];
            lp += (double)best[j];
        }
        atomicAdd(loss_acc, lp);
    }
}

// ================== shared epilogue kernels ==================
__global__ __launch_bounds__(256) void gather_kernel(const float* __restrict__ emb,
                                                     const int* __restrict__ idx_i,
                                                     float* __restrict__ zq) {
    const int blk = blockIdx.x;
    const int b = blk >> 4;
    const int t0 = (blk & 15) * 64;
    const int q = threadIdx.x & 63;
    const int dc = threadIdx.x >> 6;
    const int n = b * TT + t0 + q;
    const int k = idx_i[n];
    const f4* erow = (const f4*)(emb + (size_t)k * DD + dc * 64);
    #pragma unroll
    for (int jj = 0; jj < 16; ++jj) {
        const f4 v = erow[jj];
        const int d = dc * 64 + jj * 4;
        zq[(size_t)(b * DD + d + 0) * TT + t0 + q] = v.x;
        zq[(size_t)(b * DD + d + 1) * TT + t0 + q] = v.y;
        zq[(size_t)(b * DD + d + 2) * TT + t0 + q] = v.z;
        zq[(size_t)(b * DD + d + 3) * TT + t0 + q] = v.w;
    }
}

__global__ void fin_kernel(const double* __restrict__ loss_acc,
                           float* __restrict__ out_loss) {
    out_loss[0] = (float)(loss_acc[0] * (1.0 / ((double)BB * DD * TT)));
}

extern "C" void kernel_launch(void* const* d_in, const int* in_sizes, int n_in,
                              void* d_out, int out_size, void* d_ws, size_t ws_size,
                              hipStream_t stream) {
    const float* z_e = (const float*)d_in[0];
    const float* emb = (const float*)d_in[1];

    float* out      = (float*)d_out;
    float* zq       = out;
    float* out_loss = out + (size_t)BB * DD * TT;
    float* out_idx  = out_loss + 1;

    char* ws = (char*)d_ws;
    double* loss_acc = (double*)(ws + WS_LOSS);
    float*  Bf       = (float*)(ws + WS_BF);
    float*  Af       = (float*)(ws + WS_AF);
    int*    idx_i    = (int*)(ws + WS_IDX);

    hipMemsetAsync(d_ws, 0, 1088, stream);
    bsum_kernel<<<KK / 256, 256, 0, stream>>>(emb, Bf);

    if (ws_size >= (size_t)WS_NEED) {
        int*    cnt    = (int*)(ws + WS_CNT);
        int*    bcnt   = (int*)(ws + WS_BCNT);
        unsigned long long* winner = (unsigned long long*)(ws + WS_WIN);
        float*  zt     = (float*)(ws + WS_ZT);
        float*  tmp_min = (float*)(ws + WS_TMIN);
        int*    bucket = (int*)(ws + WS_BKT);
        int*    list   = (int*)(ws + WS_LIST);
        unsigned short* zf = (unsigned short*)(ws + WS_ZF);
        unsigned short* ef = (unsigned short*)(ws + WS_EF);

        fusedz_kernel<<<(BB * TT) / 64, 256, 0, stream>>>(z_e, zt, zf, Af);
        convef_kernel<<<(KK * DD / 8) / 256, 256, 0, stream>>>(emb, ef);
        mfma1_kernel<<<(BB * TT / 128) * 16, 256, 0, stream>>>(zf, ef, Af, Bf, tmp_min);
        select_kernel<<<(BB * TT) / 4, 256, 0, stream>>>(tmp_min, bcnt, bucket, list, cnt, winner);
        rescan_bucket_kernel<<<256 * 8, 256, 0, stream>>>(zt, emb, Af, Bf, bcnt, bucket, winner);
        rescan2_kernel<<<128, 256, 0, stream>>>(zt, emb, Af, Bf, list, cnt, winner);
        final_kernel<<<(BB * TT) / 256, 256, 0, stream>>>(winner, out_idx, idx_i, loss_acc);
    } else {
        asum_kernel<<<(BB * TT) / 256, 256, 0, stream>>>(z_e, Af);
        score5_kernel<<<(BB * TT) / 32, 256, 0, stream>>>(z_e, emb, Bf, Af, out_idx, idx_i, loss_acc);
    }

    gather_kernel<<<(BB * TT) / 64, 256, 0, stream>>>(emb, idx_i, zq);
    fin_kernel<<<1, 1, 0, stream>>>(loss_acc, out_loss);
}